// Round 11
// baseline (194.514 us; speedup 1.0000x reference)
//
#include <hip/hip_runtime.h>
#include <hip/hip_bf16.h>

// Problem constants
#define B_   2
#define T_   2048
#define D_   1024
#define NH_  16
#define HD_  64
#define MROWS (B_*T_)              // 4096
#define HEADELEMS (B_*NH_*T_*HD_)  // 4194304 per Q/K/V tensor

// exp(s/8) = 2^(s * 0.125 * log2 e); folded into Q at the QKV epilogue
#define QSCALE 0.180336880f

typedef unsigned short u16;
typedef unsigned int   u32;

typedef float f32x4  __attribute__((ext_vector_type(4)));
typedef short bf16x8 __attribute__((ext_vector_type(8)));

// async global->LDS, 16 B/lane; LDS dest MUST be wave-uniform (base+lane*16)
#define GLP(g, l) __builtin_amdgcn_global_load_lds(                         \
    (const __attribute__((address_space(1))) void*)(g),                     \
    (__attribute__((address_space(3))) void*)(l), 16, 0, 0)

struct Fc { static constexpr bool value = false; };
struct Tc { static constexpr bool value = true;  };

__device__ __forceinline__ u16 f2bf(float f) {
    u32 x = __float_as_uint(f);
    u32 r = (x + 0x7fffu + ((x >> 16) & 1u)) >> 16;
    return (u16)r;
}
// packed fp32x2 -> bf16x2
__device__ __forceinline__ u32 pkbf2(float a, float b) {
    __hip_bfloat162 h = __float22bfloat162_rn(make_float2(a, b));
    union { __hip_bfloat162 h2; u32 u; } cv; cv.h2 = h; return cv.u;
}

// ---------------------------------------------------------------------------
// Fused prep: [0,4096) x fp32->bf16; [4096,4864) Wqkv -> bf16 T;
// [4864,5120) Wproj -> bf16 T (only launched on the huge-ws path).
// ---------------------------------------------------------------------------
__device__ __forceinline__ void transpose_tile(const float* in, u16* out,
                                               int K, int N, int bx, int by,
                                               int t, float (*Ts)[65])
{
    const int n0 = bx * 64;
    const int k0 = by * 64;
    #pragma unroll
    for (int pass = 0; pass < 4; pass++) {
        const int r = pass * 16 + (t >> 4);
        const int c = (t & 15) * 4;
        float4 v = *(const float4*)(in + (size_t)(k0 + r) * N + n0 + c);
        Ts[r][c] = v.x; Ts[r][c+1] = v.y; Ts[r][c+2] = v.z; Ts[r][c+3] = v.w;
    }
    __syncthreads();
    #pragma unroll
    for (int pass = 0; pass < 2; pass++) {
        const int nn = pass * 32 + (t >> 3);
        const int kk = (t & 7) * 8;
        u16 o[8];
        #pragma unroll
        for (int j = 0; j < 8; j++) o[j] = f2bf(Ts[kk + j][nn]);
        *(uint4*)(out + (size_t)(n0 + nn) * K + k0 + kk) = *(const uint4*)o;
    }
}

__global__ __launch_bounds__(256)
void prep_kernel(const float* __restrict__ x, const float* __restrict__ Wqkv,
                 const float* __restrict__ Wproj, u16* __restrict__ xb,
                 u16* __restrict__ WqkvT, u16* __restrict__ WprojT)
{
    __shared__ float Ts[64][65];
    const int bid = blockIdx.x;
    const int t   = threadIdx.x;
    if (bid < 4096) {
        int i = bid * 256 + t;
        float4 v = ((const float4*)x)[i];
        ushort4 o;
        o.x = f2bf(v.x); o.y = f2bf(v.y); o.z = f2bf(v.z); o.w = f2bf(v.w);
        ((ushort4*)xb)[i] = o;
    } else if (bid < 4096 + 768) {
        int tb = bid - 4096;                   // [3072][1024] T
        transpose_tile(Wqkv, WqkvT, D_, 3*D_, tb % 48, tb / 48, t, Ts);
    } else {
        int tb = bid - 4864;                   // [1024][1024] T
        transpose_tile(Wproj, WprojT, D_, D_, tb % 16, tb / 16, t, Ts);
    }
}

__global__ __launch_bounds__(256)
void transpose_conv_kernel(const float* __restrict__ in, u16* __restrict__ out,
                           int K, int N)
{
    __shared__ float Ts[64][65];
    transpose_tile(in, out, K, N, blockIdx.x, blockIdx.y, threadIdx.x, Ts);
}

// ---------------------------------------------------------------------------
// MFMA GEMM (r10 config, VERIFIED BEST — do not touch): counted-vmcnt
// double-buffered pipeline on 128x128 / 4-wave / BK=64, 2D grid (proven L2
// pattern). Per K-step: STAGE(buf^1, k+1) -> vmcnt(8) -> s_barrier ->
// ds_read + 32 MFMA -> lgkmcnt(0) + s_barrier. Never drains vmcnt to 0
// in-loop. Staging: per-lane global row srow=t>>3, pre-swizzled seg
// ((t&7)^(srow&7)); wave-uniform LDS base wave*8 (+32/64/96). Frag read
// col (quad^(l16&7))*8 ^ (kk*32). Conflicts = 0 (r9/r10-verified).
// MODE 0: fp32 row-major + bias. MODE 1: scatter bf16 Q(*QSCALE),K | V^T.
// ---------------------------------------------------------------------------
template <int MODE>
__global__ __launch_bounds__(256)
void gemm_mfma(const u16* __restrict__ A, const u16* __restrict__ BT,
               const float* __restrict__ bias, void* __restrict__ outv,
               int M, int N, int K)
{
    __shared__ u16 As[2][128][64];
    __shared__ u16 Bs[2][128][64];

    const int t    = threadIdx.x;
    const int wave = t >> 6;
    const int lane = t & 63;
    const int l16  = lane & 15;
    const int quad = lane >> 4;

    const int m0 = blockIdx.y * 128;
    const int n0 = blockIdx.x * 128;
    const int mb = (wave >> 1) * 64;
    const int nb = (wave & 1) * 64;

    const int srow = t >> 3;                     // 0..31 (block-wide)
    const int sseg = ((t & 7) ^ (srow & 7)) * 8; // pre-swizzled k-offset
    const int rw8  = wave * 8;                   // wave-uniform LDS row base

    const u16* gA = A  + (size_t)(m0 + srow) * K + sseg;
    const u16* gB = BT + (size_t)(n0 + srow) * K + sseg;

    const int fragcol = (quad ^ (l16 & 7)) * 8;

    f32x4 acc[4][4];
    #pragma unroll
    for (int i = 0; i < 4; i++)
        #pragma unroll
        for (int j = 0; j < 4; j++) acc[i][j] = (f32x4){0,0,0,0};

    auto STAGE = [&](int buf, int k0) {
        GLP(gA + k0,          &As[buf][rw8     ][0]);
        GLP(gA + k0 + 32*K,   &As[buf][rw8 + 32][0]);
        GLP(gA + k0 + 64*K,   &As[buf][rw8 + 64][0]);
        GLP(gA + k0 + 96*K,   &As[buf][rw8 + 96][0]);
        GLP(gB + k0,          &Bs[buf][rw8     ][0]);
        GLP(gB + k0 + 32*K,   &Bs[buf][rw8 + 32][0]);
        GLP(gB + k0 + 64*K,   &Bs[buf][rw8 + 64][0]);
        GLP(gB + k0 + 96*K,   &Bs[buf][rw8 + 96][0]);
    };

    const int nk = K >> 6;

    STAGE(0, 0);
    asm volatile("s_waitcnt vmcnt(0)" ::: "memory");
    __builtin_amdgcn_s_barrier();

    for (int kt = 0; kt < nk; ++kt) {
        const int cur = kt & 1;
        const bool have_next = (kt + 1 < nk);

        if (have_next) {
            STAGE(cur ^ 1, (kt + 1) << 6);
            asm volatile("s_waitcnt vmcnt(8)" ::: "memory");
        } else {
            asm volatile("s_waitcnt vmcnt(0)" ::: "memory");
        }
        __builtin_amdgcn_s_barrier();

        #pragma unroll
        for (int kk = 0; kk < 2; kk++) {
            const int fc = fragcol ^ (kk << 5);
            bf16x8 af[4], bfr[4];
            #pragma unroll
            for (int i = 0; i < 4; i++)
                af[i] = *(const bf16x8*)&As[cur][mb + i*16 + l16][fc];
            #pragma unroll
            for (int j = 0; j < 4; j++)
                bfr[j] = *(const bf16x8*)&Bs[cur][nb + j*16 + l16][fc];

            #pragma unroll
            for (int i = 0; i < 4; i++)
                #pragma unroll
                for (int j = 0; j < 4; j++)
                    acc[i][j] = __builtin_amdgcn_mfma_f32_16x16x32_bf16(
                        af[i], bfr[j], acc[i][j], 0, 0, 0);
        }

        if (have_next) {
            asm volatile("s_waitcnt lgkmcnt(0)" ::: "memory");
            __builtin_amdgcn_s_barrier();
        }
    }

    if (MODE == 0) {
        #pragma unroll
        for (int j = 0; j < 4; j++) {
            const int n = n0 + nb + j*16 + l16;
            const float bv = bias[n];
            #pragma unroll
            for (int i = 0; i < 4; i++) {
                #pragma unroll
                for (int r = 0; r < 4; r++) {
                    const int m = m0 + mb + i*16 + quad*4 + r;
                    ((float*)outv)[(size_t)m * N + n] = acc[i][j][r] + bv;
                }
            }
        }
    } else {
        const int sec = n0 >> 10;        // block-uniform: 0=q 1=k 2=v
        const int b   = m0 >> 11;        // block-uniform batch index
        const int tb  = m0 & 2047;
        if (sec < 2) {
            const float qs = (sec == 0) ? QSCALE : 1.f;
            #pragma unroll
            for (int j = 0; j < 4; j++) {
                const int n  = n0 + nb + j*16 + l16;
                const float bv = bias[n];
                const int dd = n & 1023;
                const int h  = dd >> 6;
                const int hd = dd & 63;
                u16* op = (u16*)outv + (size_t)sec * HEADELEMS
                        + ((size_t)(b*NH_ + h)) * T_ * HD_ + hd;
                #pragma unroll
                for (int i = 0; i < 4; i++) {
                    #pragma unroll
                    for (int r = 0; r < 4; r++) {
                        const int tt = tb + mb + i*16 + quad*4 + r;
                        op[(size_t)tt * HD_] = f2bf((acc[i][j][r] + bv) * qs);
                    }
                }
            }
        } else {
            #pragma unroll
            for (int j = 0; j < 4; j++) {
                const int n  = n0 + nb + j*16 + l16;
                const float bv = bias[n];
                const int dd = n & 1023;
                const int h  = dd >> 6;
                const int hd = dd & 63;
                u16* vp = (u16*)outv + (size_t)2 * HEADELEMS
                        + ((size_t)(b*NH_ + h)) * T_ * HD_
                        + (size_t)hd * T_ + tb + mb;
                #pragma unroll
                for (int i = 0; i < 4; i++) {
                    u16 o[4];
                    #pragma unroll
                    for (int r = 0; r < 4; r++) o[r] = f2bf(acc[i][j][r] + bv);
                    *(uint2*)(vp + i*16 + quad*4) = *(const uint2*)o;
                }
            }
        }
    }
}

// ---------------------------------------------------------------------------
// MFMA flash attention v8. Round-19 change: PAIRED Q-TILES per block.
// r10 profile: attn 46.9 µs, MfmaUtil 15.5, VALUBusy 34, Occ 22.5% —
// tail/latency-bound (triangular work: short-qt blocks drain, long-qt
// block runs the tail near-alone). Fix: one block handles the complementary
// pair (qt=p, qt=31-p); every block = exactly 33 tile-computes -> uniform
// duration (no tail). Shared k-prefix (kt<=p) stages each K/V tile ONCE
// for TWO Q-tiles: 26% fewer staged tiles, 2x MFMA per barrier in prefix,
// and the A/B chains are independent -> in-wave ILP (B's QK MFMAs issue
// under A's exp/shuffle VALU; T15 mechanism). Grid (32 hb, 16 pairs) =
// 512 blocks = 2/CU. LDS unchanged 32 KB ([64][64] XOR-seg, conflict-free
// reads/writes). VGPR ~68 -> ~160 (2x fragments+accum) — still fine.
// ---------------------------------------------------------------------------
__global__ __launch_bounds__(256)
void attn_mfma_kernel(const u16* __restrict__ Q, const u16* __restrict__ K,
                      const u16* __restrict__ VT, u16* __restrict__ y1)
{
    __shared__ u16 Ks[2][64][64];     // [buf][key][d]   (XOR-seg swizzled)
    __shared__ u16 Vs[2][64][64];     // [buf][d][key]   (XOR-seg swizzled)

    const int t    = threadIdx.x;
    const int wave = t >> 6;
    const int lane = t & 63;
    const int l16  = lane & 15;
    const int quad = lane >> 4;

    const int hb = blockIdx.x;                 // b*NH + h
    const int p  = blockIdx.y;                 // 0..15
    const int qta = p;                         // small q-tile
    const int qtb = 31 - p;                    // large q-tile (qta < qtb)
    const int b  = hb >> 4;
    const int h  = hb & 15;
    const size_t base = (size_t)hb * T_ * HD_;

    const int qwA = qta * 64 + wave * 16;      // first q-row, tile A
    const int qwB = qtb * 64 + wave * 16;      // first q-row, tile B

    // Q fragments for both tiles (Q pre-scaled by QSCALE)
    bf16x8 qfA[2], qfB[2];
    {
        const u16* qa = Q + base + (size_t)(qwA + l16) * HD_ + quad * 8;
        qfA[0] = *(const bf16x8*)(qa);
        qfA[1] = *(const bf16x8*)(qa + 32);
        const u16* qb = Q + base + (size_t)(qwB + l16) * HD_ + quad * 8;
        qfB[0] = *(const bf16x8*)(qb);
        qfB[1] = *(const bf16x8*)(qb + 32);
    }

    bf16x8 onesf;
    #pragma unroll
    for (int i = 0; i < 8; i++) onesf[i] = (short)0x3F80;

    f32x4 oA[4], oB[4];
    #pragma unroll
    for (int d = 0; d < 4; d++) { oA[d] = (f32x4){0,0,0,0}; oB[d] = (f32x4){0,0,0,0}; }
    f32x4 acclA = (f32x4){0,0,0,0};
    f32x4 acclB = (f32x4){0,0,0,0};

    const int nsteps = qtb + 1;                // 32 - p staged tiles

    const int srow = t >> 3;                   // 0..31
    const int scol = (t & 7) * 8;              // logical seg * 8
    const int sst  = (((t & 7) ^ (srow & 7)) * 8);  // stored (swizzled) col

    // fragment-read swizzled columns
    const int fs0 = (quad ^ (l16 & 7)) * 8;
    const int fs1 = fs0 ^ 32;

    // shuffle sources for C->A redistribution (r10-verified)
    const int srcA  = l16 + ((quad & 1) << 5);
    const int srcB  = srcA + 16;
    const bool selhi = (quad >> 1) != 0;

    // stage tile 0
    uint4 kr0, kr1, vr0, vr1;
    {
        const u16* kp = K + base + (size_t)srow * HD_ + scol;
        kr0 = *(const uint4*)kp;
        kr1 = *(const uint4*)(kp + 32 * HD_);
        const u16* vp = VT + base + (size_t)srow * T_ + scol;
        vr0 = *(const uint4*)vp;
        vr1 = *(const uint4*)(vp + 32 * T_);
        *(uint4*)&Ks[0][srow][sst]      = kr0;
        *(uint4*)&Ks[0][srow + 32][sst] = kr1;
        *(uint4*)&Vs[0][srow][sst]      = vr0;
        *(uint4*)&Vs[0][srow + 32][sst] = vr1;
    }
    __syncthreads();

    // one Q-tile's work against the staged K/V tile
    auto compute_tile = [&](int cur, int k0, auto mc, const bf16x8* qf,
                            f32x4* o, f32x4& accl, int qw0) {
        constexpr bool MASKED = decltype(mc)::value;
        // S^T = K_tile . Q^T
        f32x4 st[4];
        __builtin_amdgcn_s_setprio(1);
        #pragma unroll
        for (int j = 0; j < 4; j++) {
            bf16x8 kf0 = *(const bf16x8*)&Ks[cur][j*16 + l16][fs0];
            bf16x8 kf1 = *(const bf16x8*)&Ks[cur][j*16 + l16][fs1];
            f32x4 z = {0,0,0,0};
            z = __builtin_amdgcn_mfma_f32_16x16x32_bf16(kf0, qf[0], z, 0, 0, 0);
            st[j] = __builtin_amdgcn_mfma_f32_16x16x32_bf16(kf1, qf[1], z, 0, 0, 0);
        }
        __builtin_amdgcn_s_setprio(0);

        // exp2 (+ mask, compile-time gated) + packed bf16
        u32 p01[4], p23[4];
        const int qi = qw0 + l16;
        #pragma unroll
        for (int j = 0; j < 4; j++) {
            const int kb = k0 + j*16 + quad*4;
            float e0 = __builtin_amdgcn_exp2f(st[j][0]);
            float e1 = __builtin_amdgcn_exp2f(st[j][1]);
            float e2 = __builtin_amdgcn_exp2f(st[j][2]);
            float e3 = __builtin_amdgcn_exp2f(st[j][3]);
            if (MASKED) {
                if (kb + 0 > qi) e0 = 0.f;
                if (kb + 1 > qi) e1 = 0.f;
                if (kb + 2 > qi) e2 = 0.f;
                if (kb + 3 > qi) e3 = 0.f;
            }
            p01[j] = pkbf2(e0, e1);
            p23[j] = pkbf2(e2, e3);
        }

        // C->A redistribution via shuffles; then ones-MFMA + PV
        bf16x8 pf[2];
        #pragma unroll
        for (int c = 0; c < 2; c++) {
            u32 t0, t1, r01, r23, r45, r67;
            t0 = (u32)__shfl((int)p01[2*c],   srcA);
            t1 = (u32)__shfl((int)p01[2*c+1], srcA);
            r01 = selhi ? t1 : t0;
            t0 = (u32)__shfl((int)p23[2*c],   srcA);
            t1 = (u32)__shfl((int)p23[2*c+1], srcA);
            r23 = selhi ? t1 : t0;
            t0 = (u32)__shfl((int)p01[2*c],   srcB);
            t1 = (u32)__shfl((int)p01[2*c+1], srcB);
            r45 = selhi ? t1 : t0;
            t0 = (u32)__shfl((int)p23[2*c],   srcB);
            t1 = (u32)__shfl((int)p23[2*c+1], srcB);
            r67 = selhi ? t1 : t0;
            union { u32 u[4]; bf16x8 v; } pk;
            pk.u[0] = r01; pk.u[1] = r23; pk.u[2] = r45; pk.u[3] = r67;
            pf[c] = pk.v;
        }
        __builtin_amdgcn_s_setprio(1);
        accl = __builtin_amdgcn_mfma_f32_16x16x32_bf16(pf[0], onesf, accl, 0, 0, 0);
        accl = __builtin_amdgcn_mfma_f32_16x16x32_bf16(pf[1], onesf, accl, 0, 0, 0);
        #pragma unroll
        for (int d = 0; d < 4; d++) {
            bf16x8 v0 = *(const bf16x8*)&Vs[cur][d*16 + l16][fs0];
            bf16x8 v1 = *(const bf16x8*)&Vs[cur][d*16 + l16][fs1];
            o[d] = __builtin_amdgcn_mfma_f32_16x16x32_bf16(pf[0], v0, o[d], 0, 0, 0);
            o[d] = __builtin_amdgcn_mfma_f32_16x16x32_bf16(pf[1], v1, o[d], 0, 0, 0);
        }
        __builtin_amdgcn_s_setprio(0);
    };

    for (int kt = 0; kt < nsteps; kt++) {
        const int cur = kt & 1;
        const int k0  = kt * 64;
        const bool have_next = (kt + 1 < nsteps);

        if (have_next) {
            const u16* kp = K + base + (size_t)(k0 + 64 + srow) * HD_ + scol;
            kr0 = *(const uint4*)kp;
            kr1 = *(const uint4*)(kp + 32 * HD_);
            const u16* vp = VT + base + (size_t)srow * T_ + k0 + 64 + scol;
            vr0 = *(const uint4*)vp;
            vr1 = *(const uint4*)(vp + 32 * T_);
        }

        // shared-prefix: both Q-tiles consume the staged tile (back-to-back
        // in one basic block -> compiler interleaves the two indep chains)
        if (kt < qta) {
            compute_tile(cur, k0, Fc{}, qfA, oA, acclA, qwA);
            compute_tile(cur, k0, Fc{}, qfB, oB, acclB, qwB);
        } else if (kt == qta) {
            compute_tile(cur, k0, Tc{}, qfA, oA, acclA, qwA);
            compute_tile(cur, k0, Fc{}, qfB, oB, acclB, qwB);
        } else if (kt < qtb) {
            compute_tile(cur, k0, Fc{}, qfB, oB, acclB, qwB);
        } else {
            compute_tile(cur, k0, Tc{}, qfB, oB, acclB, qwB);
        }

        if (have_next) {
            const int nxt = cur ^ 1;
            *(uint4*)&Ks[nxt][srow][sst]      = kr0;
            *(uint4*)&Ks[nxt][srow + 32][sst] = kr1;
            *(uint4*)&Vs[nxt][srow][sst]      = vr0;
            *(uint4*)&Vs[nxt][srow + 32][sst] = vr1;
            __syncthreads();
        }
    }

    // epilogue: normalize by ones-MFMA row sums; y1[B,T,D] bf16 — both tiles
    #pragma unroll
    for (int r = 0; r < 4; r++) {
        const float invA = 1.f / acclA[r];
        const int qiA = qwA + quad*4 + r;
        u16* ya = y1 + ((size_t)(b * T_ + qiA)) * D_ + h * HD_ + l16;
        ya[0]  = f2bf(oA[0][r] * invA);
        ya[16] = f2bf(oA[1][r] * invA);
        ya[32] = f2bf(oA[2][r] * invA);
        ya[48] = f2bf(oA[3][r] * invA);

        const float invB = 1.f / acclB[r];
        const int qiB = qwB + quad*4 + r;
        u16* yb = y1 + ((size_t)(b * T_ + qiB)) * D_ + h * HD_ + l16;
        yb[0]  = f2bf(oB[0][r] * invB);
        yb[16] = f2bf(oB[1][r] * invB);
        yb[32] = f2bf(oB[2][r] * invB);
        yb[48] = f2bf(oB[3][r] * invB);
    }
}

// ---------------------------------------------------------------------------
// Choreography, three ws tiers:
//  huge (>= 3*QKV + y1 + WprojT = ~35.7 MB): prep also transposes Wproj into
//    ws; attn -> y1 in ws; 4 dispatches, no memcpy.
//  big  (>= 3*QKV + y1 = ~33.5 MB): y1 in ws; WprojT over dead K after attn.
//  small: y1 over dead xb in d_out; memcpy to dead VT; WprojT over dead K.
// ---------------------------------------------------------------------------
extern "C" void kernel_launch(void* const* d_in, const int* in_sizes, int n_in,
                              void* d_out, int out_size, void* d_ws, size_t ws_size,
                              hipStream_t stream)
{
    const float* x     = (const float*)d_in[0];
    const float* Wqkv  = (const float*)d_in[1];
    const float* bqkv  = (const float*)d_in[2];
    const float* Wproj = (const float*)d_in[3];
    const float* bproj = (const float*)d_in[4];

    u16* scratch = (u16*)d_out;
    u16* xb      = scratch;
    u16* WqkvT   = scratch + (size_t)MROWS * D_;

    const size_t Y1E = (size_t)MROWS * D_;   // y1 elems (== HEADELEMS)
    const size_t WPE = (size_t)D_ * D_;      // WprojT elems

    u16* qkv = (u16*)d_ws;
    u16* Qp  = qkv;
    u16* Kp  = qkv + (size_t)HEADELEMS;
    u16* Vtp = qkv + (size_t)2 * HEADELEMS;

    const bool huge = ws_size >= ((size_t)3 * HEADELEMS + Y1E + WPE) * 2;
    const bool big  = ws_size >= ((size_t)3 * HEADELEMS + Y1E) * 2;

    u16* y1b    = big ? qkv + (size_t)3 * HEADELEMS : scratch;
    u16* y1g    = big ? y1b : Vtp;
    u16* WprojT = huge ? qkv + (size_t)3 * HEADELEMS + Y1E : Kp;

    // 1) fused prep
    prep_kernel<<<huge ? 5120 : 4864, 256, 0, stream>>>(
        x, Wqkv, Wproj, xb, WqkvT, WprojT);

    // 2) QKV GEMM -> Q(prescaled) | K | VT (bf16) in ws; 2D grid, pipelined
    gemm_mfma<1><<<dim3(3*D_/128, MROWS/128), 256, 0, stream>>>(
        xb, WqkvT, bqkv, (void*)qkv, MROWS, 3*D_, D_);

    // 3) attention -> y1 bf16; grid (hb=32, pairs=16), paired q-tiles
    attn_mfma_kernel<<<dim3(NH_*B_, 16), 256, 0, stream>>>(Qp, Kp, Vtp, y1b);

    // 4) Wproj transpose (non-huge paths; K dead now)
    if (!huge)
        transpose_conv_kernel<<<dim3(D_/64, D_/64), 256, 0, stream>>>(
            Wproj, WprojT, D_, D_);

    // 5) small-ws fallback: move y1 out of d_out
    if (!big)
        (void)hipMemcpyAsync(y1g, y1b, Y1E * sizeof(u16),
                             hipMemcpyDeviceToDevice, stream);

    // 6) output projection -> fp32 d_out; 2D grid
    gemm_mfma<0><<<dim3(D_/128, MROWS/128), 256, 0, stream>>>(
        y1g, WprojT, bproj, d_out, MROWS, D_, D_);
}

// Round 12
// 191.471 us; speedup vs baseline: 1.0159x; 1.0159x over previous
//
#include <hip/hip_runtime.h>
#include <hip/hip_bf16.h>

// Problem constants
#define B_   2
#define T_   2048
#define D_   1024
#define NH_  16
#define HD_  64
#define MROWS (B_*T_)              // 4096
#define HEADELEMS (B_*NH_*T_*HD_)  // 4194304 per Q/K/V tensor

// exp(s/8) = 2^(s * 0.125 * log2 e); folded into Q at the QKV epilogue
#define QSCALE 0.180336880f

typedef unsigned short u16;
typedef unsigned int   u32;

typedef float f32x4  __attribute__((ext_vector_type(4)));
typedef short bf16x8 __attribute__((ext_vector_type(8)));

// async global->LDS, 16 B/lane; LDS dest MUST be wave-uniform (base+lane*16)
#define GLP(g, l) __builtin_amdgcn_global_load_lds(                         \
    (const __attribute__((address_space(1))) void*)(g),                     \
    (__attribute__((address_space(3))) void*)(l), 16, 0, 0)

struct Fc { static constexpr bool value = false; };
struct Tc { static constexpr bool value = true;  };

__device__ __forceinline__ u16 f2bf(float f) {
    u32 x = __float_as_uint(f);
    u32 r = (x + 0x7fffu + ((x >> 16) & 1u)) >> 16;
    return (u16)r;
}
// packed fp32x2 -> bf16x2
__device__ __forceinline__ u32 pkbf2(float a, float b) {
    __hip_bfloat162 h = __float22bfloat162_rn(make_float2(a, b));
    union { __hip_bfloat162 h2; u32 u; } cv; cv.h2 = h; return cv.u;
}

// ---------------------------------------------------------------------------
// Fused prep: [0,4096) x fp32->bf16; [4096,4864) Wqkv -> bf16 T;
// [4864,5120) Wproj -> bf16 T (only launched on the huge-ws path).
// ---------------------------------------------------------------------------
__device__ __forceinline__ void transpose_tile(const float* in, u16* out,
                                               int K, int N, int bx, int by,
                                               int t, float (*Ts)[65])
{
    const int n0 = bx * 64;
    const int k0 = by * 64;
    #pragma unroll
    for (int pass = 0; pass < 4; pass++) {
        const int r = pass * 16 + (t >> 4);
        const int c = (t & 15) * 4;
        float4 v = *(const float4*)(in + (size_t)(k0 + r) * N + n0 + c);
        Ts[r][c] = v.x; Ts[r][c+1] = v.y; Ts[r][c+2] = v.z; Ts[r][c+3] = v.w;
    }
    __syncthreads();
    #pragma unroll
    for (int pass = 0; pass < 2; pass++) {
        const int nn = pass * 32 + (t >> 3);
        const int kk = (t & 7) * 8;
        u16 o[8];
        #pragma unroll
        for (int j = 0; j < 8; j++) o[j] = f2bf(Ts[kk + j][nn]);
        *(uint4*)(out + (size_t)(n0 + nn) * K + k0 + kk) = *(const uint4*)o;
    }
}

__global__ __launch_bounds__(256)
void prep_kernel(const float* __restrict__ x, const float* __restrict__ Wqkv,
                 const float* __restrict__ Wproj, u16* __restrict__ xb,
                 u16* __restrict__ WqkvT, u16* __restrict__ WprojT)
{
    __shared__ float Ts[64][65];
    const int bid = blockIdx.x;
    const int t   = threadIdx.x;
    if (bid < 4096) {
        int i = bid * 256 + t;
        float4 v = ((const float4*)x)[i];
        ushort4 o;
        o.x = f2bf(v.x); o.y = f2bf(v.y); o.z = f2bf(v.z); o.w = f2bf(v.w);
        ((ushort4*)xb)[i] = o;
    } else if (bid < 4096 + 768) {
        int tb = bid - 4096;                   // [3072][1024] T
        transpose_tile(Wqkv, WqkvT, D_, 3*D_, tb % 48, tb / 48, t, Ts);
    } else {
        int tb = bid - 4864;                   // [1024][1024] T
        transpose_tile(Wproj, WprojT, D_, D_, tb % 16, tb / 16, t, Ts);
    }
}

__global__ __launch_bounds__(256)
void transpose_conv_kernel(const float* __restrict__ in, u16* __restrict__ out,
                           int K, int N)
{
    __shared__ float Ts[64][65];
    transpose_tile(in, out, K, N, blockIdx.x, blockIdx.y, threadIdx.x, Ts);
}

// ---------------------------------------------------------------------------
// MFMA GEMM (r10 config, VERIFIED BEST — do not touch): counted-vmcnt
// double-buffered pipeline on 128x128 / 4-wave / BK=64, 2D grid (proven L2
// pattern). Per K-step: STAGE(buf^1, k+1) -> vmcnt(8) -> s_barrier ->
// ds_read + 32 MFMA -> lgkmcnt(0) + s_barrier. Never drains vmcnt to 0
// in-loop. Staging: per-lane global row srow=t>>3, pre-swizzled seg
// ((t&7)^(srow&7)); wave-uniform LDS base wave*8 (+32/64/96). Frag read
// col (quad^(l16&7))*8 ^ (kk*32). Conflicts = 0 (r9/r10-verified).
// MODE 0: fp32 row-major + bias. MODE 1: scatter bf16 Q(*QSCALE),K | V^T.
// ---------------------------------------------------------------------------
template <int MODE>
__global__ __launch_bounds__(256)
void gemm_mfma(const u16* __restrict__ A, const u16* __restrict__ BT,
               const float* __restrict__ bias, void* __restrict__ outv,
               int M, int N, int K)
{
    __shared__ u16 As[2][128][64];
    __shared__ u16 Bs[2][128][64];

    const int t    = threadIdx.x;
    const int wave = t >> 6;
    const int lane = t & 63;
    const int l16  = lane & 15;
    const int quad = lane >> 4;

    const int m0 = blockIdx.y * 128;
    const int n0 = blockIdx.x * 128;
    const int mb = (wave >> 1) * 64;
    const int nb = (wave & 1) * 64;

    const int srow = t >> 3;                     // 0..31 (block-wide)
    const int sseg = ((t & 7) ^ (srow & 7)) * 8; // pre-swizzled k-offset
    const int rw8  = wave * 8;                   // wave-uniform LDS row base

    const u16* gA = A  + (size_t)(m0 + srow) * K + sseg;
    const u16* gB = BT + (size_t)(n0 + srow) * K + sseg;

    const int fragcol = (quad ^ (l16 & 7)) * 8;

    f32x4 acc[4][4];
    #pragma unroll
    for (int i = 0; i < 4; i++)
        #pragma unroll
        for (int j = 0; j < 4; j++) acc[i][j] = (f32x4){0,0,0,0};

    auto STAGE = [&](int buf, int k0) {
        GLP(gA + k0,          &As[buf][rw8     ][0]);
        GLP(gA + k0 + 32*K,   &As[buf][rw8 + 32][0]);
        GLP(gA + k0 + 64*K,   &As[buf][rw8 + 64][0]);
        GLP(gA + k0 + 96*K,   &As[buf][rw8 + 96][0]);
        GLP(gB + k0,          &Bs[buf][rw8     ][0]);
        GLP(gB + k0 + 32*K,   &Bs[buf][rw8 + 32][0]);
        GLP(gB + k0 + 64*K,   &Bs[buf][rw8 + 64][0]);
        GLP(gB + k0 + 96*K,   &Bs[buf][rw8 + 96][0]);
    };

    const int nk = K >> 6;

    STAGE(0, 0);
    asm volatile("s_waitcnt vmcnt(0)" ::: "memory");
    __builtin_amdgcn_s_barrier();

    for (int kt = 0; kt < nk; ++kt) {
        const int cur = kt & 1;
        const bool have_next = (kt + 1 < nk);

        if (have_next) {
            STAGE(cur ^ 1, (kt + 1) << 6);
            asm volatile("s_waitcnt vmcnt(8)" ::: "memory");
        } else {
            asm volatile("s_waitcnt vmcnt(0)" ::: "memory");
        }
        __builtin_amdgcn_s_barrier();

        #pragma unroll
        for (int kk = 0; kk < 2; kk++) {
            const int fc = fragcol ^ (kk << 5);
            bf16x8 af[4], bfr[4];
            #pragma unroll
            for (int i = 0; i < 4; i++)
                af[i] = *(const bf16x8*)&As[cur][mb + i*16 + l16][fc];
            #pragma unroll
            for (int j = 0; j < 4; j++)
                bfr[j] = *(const bf16x8*)&Bs[cur][nb + j*16 + l16][fc];

            #pragma unroll
            for (int i = 0; i < 4; i++)
                #pragma unroll
                for (int j = 0; j < 4; j++)
                    acc[i][j] = __builtin_amdgcn_mfma_f32_16x16x32_bf16(
                        af[i], bfr[j], acc[i][j], 0, 0, 0);
        }

        if (have_next) {
            asm volatile("s_waitcnt lgkmcnt(0)" ::: "memory");
            __builtin_amdgcn_s_barrier();
        }
    }

    if (MODE == 0) {
        #pragma unroll
        for (int j = 0; j < 4; j++) {
            const int n = n0 + nb + j*16 + l16;
            const float bv = bias[n];
            #pragma unroll
            for (int i = 0; i < 4; i++) {
                #pragma unroll
                for (int r = 0; r < 4; r++) {
                    const int m = m0 + mb + i*16 + quad*4 + r;
                    ((float*)outv)[(size_t)m * N + n] = acc[i][j][r] + bv;
                }
            }
        }
    } else {
        const int sec = n0 >> 10;        // block-uniform: 0=q 1=k 2=v
        const int b   = m0 >> 11;        // block-uniform batch index
        const int tb  = m0 & 2047;
        if (sec < 2) {
            const float qs = (sec == 0) ? QSCALE : 1.f;
            #pragma unroll
            for (int j = 0; j < 4; j++) {
                const int n  = n0 + nb + j*16 + l16;
                const float bv = bias[n];
                const int dd = n & 1023;
                const int h  = dd >> 6;
                const int hd = dd & 63;
                u16* op = (u16*)outv + (size_t)sec * HEADELEMS
                        + ((size_t)(b*NH_ + h)) * T_ * HD_ + hd;
                #pragma unroll
                for (int i = 0; i < 4; i++) {
                    #pragma unroll
                    for (int r = 0; r < 4; r++) {
                        const int tt = tb + mb + i*16 + quad*4 + r;
                        op[(size_t)tt * HD_] = f2bf((acc[i][j][r] + bv) * qs);
                    }
                }
            }
        } else {
            #pragma unroll
            for (int j = 0; j < 4; j++) {
                const int n  = n0 + nb + j*16 + l16;
                const float bv = bias[n];
                const int dd = n & 1023;
                const int h  = dd >> 6;
                const int hd = dd & 63;
                u16* vp = (u16*)outv + (size_t)2 * HEADELEMS
                        + ((size_t)(b*NH_ + h)) * T_ * HD_
                        + (size_t)hd * T_ + tb + mb;
                #pragma unroll
                for (int i = 0; i < 4; i++) {
                    u16 o[4];
                    #pragma unroll
                    for (int r = 0; r < 4; r++) o[r] = f2bf(acc[i][j][r] + bv);
                    *(uint2*)(vp + i*16 + quad*4) = *(const uint2*)o;
                }
            }
        }
    }
}

// ---------------------------------------------------------------------------
// MFMA flash attention v9. Round-20: r10 structure RESTORED (r11 pairing
// regressed: grid 1024->512 lost block TLP; r10's yy->qt mapping already
// balances per-CU work at 62 tiles), with ONE change: K/V staging moved
// from reg-roundtrip (8 loads + 8 ds_writes/thread-tile) to the r10-GEMM's
// PROVEN GLP counted-vmcnt pipeline: 4 GLPs/wave per tile (wave-uniform
// LDS base rw8; per-lane global row srow=t>>3 with pre-swizzled seg
// ((t&7)^(srow&7))*8 — identical algebra to the staged [64][64] XOR-seg
// layout, reads unchanged/conflict-free). Schedule per tile:
// STAGE(buf^1) -> vmcnt(4) -> barrier -> compute -> lgkmcnt(0) -> barrier.
// Never drains vmcnt in-loop. Frees ~16 VGPR + removes staging VALU from
// the 34%-busy VALU pipe.
// ---------------------------------------------------------------------------
__global__ __launch_bounds__(256)
void attn_mfma_kernel(const u16* __restrict__ Q, const u16* __restrict__ K,
                      const u16* __restrict__ VT, u16* __restrict__ y1)
{
    __shared__ u16 Ks[2][64][64];     // [buf][key][d]   (XOR-seg swizzled)
    __shared__ u16 Vs[2][64][64];     // [buf][d][key]   (XOR-seg swizzled)

    const int t    = threadIdx.x;
    const int wave = t >> 6;
    const int lane = t & 63;
    const int l16  = lane & 15;
    const int quad = lane >> 4;

    const int hb = blockIdx.x;                 // b*NH + h
    const int yy = blockIdx.y;
    const int a  = yy & 7, g = yy >> 3;
    const int qt = (g == 0) ? 31 - a : (g == 1) ? 16 + a
                 : (g == 2) ? 15 - a : a;      // balanced 4-way pairing
    const int b  = hb >> 4;
    const int h  = hb & 15;
    const size_t base = (size_t)hb * T_ * HD_;

    const int qw0 = qt * 64 + wave * 16;       // first q-row of this wave

    // Q fragment: 2 d-chunks (Q pre-scaled by QSCALE)
    bf16x8 qf[2];
    {
        const u16* qp = Q + base + (size_t)(qw0 + l16) * HD_ + quad * 8;
        qf[0] = *(const bf16x8*)(qp);
        qf[1] = *(const bf16x8*)(qp + 32);
    }

    bf16x8 onesf;
    #pragma unroll
    for (int i = 0; i < 8; i++) onesf[i] = (short)0x3F80;

    f32x4 o[4];
    #pragma unroll
    for (int d = 0; d < 4; d++) o[d] = (f32x4){0,0,0,0};
    f32x4 accl = (f32x4){0,0,0,0};

    const int nsteps = qt + 1;                 // uniform across waves

    // GLP staging: per-lane global row srow, pre-swizzled seg; wave-uniform
    // LDS base rw8. Stored seg s at row r holds logical s^(r&7).
    const int srow = t >> 3;                   // 0..31
    const int sseg = ((t & 7) ^ (srow & 7)) * 8;
    const int rw8  = wave * 8;

    const u16* gK = K  + base + (size_t)srow * HD_ + sseg;   // key-row major
    const u16* gV = VT + base + (size_t)srow * T_  + sseg;   // d-row major

    // fragment-read swizzled columns (unchanged, conflict-free)
    const int fs0 = (quad ^ (l16 & 7)) * 8;
    const int fs1 = fs0 ^ 32;

    // shuffle sources for C->A redistribution (r10-verified)
    const int srcA  = l16 + ((quad & 1) << 5);
    const int srcB  = srcA + 16;
    const bool selhi = (quad >> 1) != 0;

    // stage tile k0 (keys k0..k0+63) into buf: K rows k0+srow / +32;
    // V^T rows srow / srow+32 at col k0
    auto STAGE = [&](int buf, int k0) {
        GLP(gK + (size_t)(k0     ) * HD_, &Ks[buf][rw8     ][0]);
        GLP(gK + (size_t)(k0 + 32) * HD_, &Ks[buf][rw8 + 32][0]);
        GLP(gV + k0,                      &Vs[buf][rw8     ][0]);
        GLP(gV + k0 + 32 * T_,            &Vs[buf][rw8 + 32][0]);
    };

    auto compute_tile = [&](int cur, int k0, auto mc) {
        constexpr bool MASKED = decltype(mc)::value;
        // S^T = K_tile . Q^T
        f32x4 st[4];
        __builtin_amdgcn_s_setprio(1);
        #pragma unroll
        for (int j = 0; j < 4; j++) {
            bf16x8 kf0 = *(const bf16x8*)&Ks[cur][j*16 + l16][fs0];
            bf16x8 kf1 = *(const bf16x8*)&Ks[cur][j*16 + l16][fs1];
            f32x4 z = {0,0,0,0};
            z = __builtin_amdgcn_mfma_f32_16x16x32_bf16(kf0, qf[0], z, 0, 0, 0);
            st[j] = __builtin_amdgcn_mfma_f32_16x16x32_bf16(kf1, qf[1], z, 0, 0, 0);
        }
        __builtin_amdgcn_s_setprio(0);

        // exp2 (+ mask, compile-time gated) + packed bf16
        u32 p01[4], p23[4];
        const int qi = qw0 + l16;
        #pragma unroll
        for (int j = 0; j < 4; j++) {
            const int kb = k0 + j*16 + quad*4;
            float e0 = __builtin_amdgcn_exp2f(st[j][0]);
            float e1 = __builtin_amdgcn_exp2f(st[j][1]);
            float e2 = __builtin_amdgcn_exp2f(st[j][2]);
            float e3 = __builtin_amdgcn_exp2f(st[j][3]);
            if (MASKED) {
                if (kb + 0 > qi) e0 = 0.f;
                if (kb + 1 > qi) e1 = 0.f;
                if (kb + 2 > qi) e2 = 0.f;
                if (kb + 3 > qi) e3 = 0.f;
            }
            p01[j] = pkbf2(e0, e1);
            p23[j] = pkbf2(e2, e3);
        }

        // C->A redistribution via shuffles; then ones-MFMA + PV
        bf16x8 pf[2];
        #pragma unroll
        for (int c = 0; c < 2; c++) {
            u32 t0, t1, r01, r23, r45, r67;
            t0 = (u32)__shfl((int)p01[2*c],   srcA);
            t1 = (u32)__shfl((int)p01[2*c+1], srcA);
            r01 = selhi ? t1 : t0;
            t0 = (u32)__shfl((int)p23[2*c],   srcA);
            t1 = (u32)__shfl((int)p23[2*c+1], srcA);
            r23 = selhi ? t1 : t0;
            t0 = (u32)__shfl((int)p01[2*c],   srcB);
            t1 = (u32)__shfl((int)p01[2*c+1], srcB);
            r45 = selhi ? t1 : t0;
            t0 = (u32)__shfl((int)p23[2*c],   srcB);
            t1 = (u32)__shfl((int)p23[2*c+1], srcB);
            r67 = selhi ? t1 : t0;
            union { u32 u[4]; bf16x8 v; } pk;
            pk.u[0] = r01; pk.u[1] = r23; pk.u[2] = r45; pk.u[3] = r67;
            pf[c] = pk.v;
        }
        __builtin_amdgcn_s_setprio(1);
        accl = __builtin_amdgcn_mfma_f32_16x16x32_bf16(pf[0], onesf, accl, 0, 0, 0);
        accl = __builtin_amdgcn_mfma_f32_16x16x32_bf16(pf[1], onesf, accl, 0, 0, 0);
        #pragma unroll
        for (int d = 0; d < 4; d++) {
            bf16x8 v0 = *(const bf16x8*)&Vs[cur][d*16 + l16][fs0];
            bf16x8 v1 = *(const bf16x8*)&Vs[cur][d*16 + l16][fs1];
            o[d] = __builtin_amdgcn_mfma_f32_16x16x32_bf16(pf[0], v0, o[d], 0, 0, 0);
            o[d] = __builtin_amdgcn_mfma_f32_16x16x32_bf16(pf[1], v1, o[d], 0, 0, 0);
        }
        __builtin_amdgcn_s_setprio(0);
    };

    // prologue: tile 0 -> buf 0, full drain once
    STAGE(0, 0);
    asm volatile("s_waitcnt vmcnt(0)" ::: "memory");
    __builtin_amdgcn_s_barrier();

    for (int kt = 0; kt < nsteps; kt++) {
        const int cur = kt & 1;
        const int k0  = kt * 64;
        const bool have_next = (kt + 1 < nsteps);

        if (have_next) {
            STAGE(cur ^ 1, k0 + 64);
            // wait ONLY tile kt's 4 GLPs; the 4 just-issued stay in flight
            asm volatile("s_waitcnt vmcnt(4)" ::: "memory");
        } else {
            asm volatile("s_waitcnt vmcnt(0)" ::: "memory");
        }
        __builtin_amdgcn_s_barrier();

        if (kt < qt) compute_tile(cur, k0, Fc{});
        else         compute_tile(cur, k0, Tc{});

        if (have_next) {
            // this wave's LDS reads (ds_read + bpermute) complete before
            // any wave's next STAGE overwrites buf[cur]
            asm volatile("s_waitcnt lgkmcnt(0)" ::: "memory");
            __builtin_amdgcn_s_barrier();
        }
    }

    // epilogue: normalize by ones-MFMA row sums; y1[B,T,D] bf16
    #pragma unroll
    for (int r = 0; r < 4; r++) {
        const float inv = 1.f / accl[r];
        const int qi = qw0 + quad*4 + r;
        u16* yp = y1 + ((size_t)(b * T_ + qi)) * D_ + h * HD_ + l16;
        yp[0]  = f2bf(o[0][r] * inv);
        yp[16] = f2bf(o[1][r] * inv);
        yp[32] = f2bf(o[2][r] * inv);
        yp[48] = f2bf(o[3][r] * inv);
    }
}

// ---------------------------------------------------------------------------
// Choreography, three ws tiers:
//  huge (>= 3*QKV + y1 + WprojT = ~35.7 MB): prep also transposes Wproj into
//    ws; attn -> y1 in ws; 4 dispatches, no memcpy.
//  big  (>= 3*QKV + y1 = ~33.5 MB): y1 in ws; WprojT over dead K after attn.
//  small: y1 over dead xb in d_out; memcpy to dead VT; WprojT over dead K.
// ---------------------------------------------------------------------------
extern "C" void kernel_launch(void* const* d_in, const int* in_sizes, int n_in,
                              void* d_out, int out_size, void* d_ws, size_t ws_size,
                              hipStream_t stream)
{
    const float* x     = (const float*)d_in[0];
    const float* Wqkv  = (const float*)d_in[1];
    const float* bqkv  = (const float*)d_in[2];
    const float* Wproj = (const float*)d_in[3];
    const float* bproj = (const float*)d_in[4];

    u16* scratch = (u16*)d_out;
    u16* xb      = scratch;
    u16* WqkvT   = scratch + (size_t)MROWS * D_;

    const size_t Y1E = (size_t)MROWS * D_;   // y1 elems (== HEADELEMS)
    const size_t WPE = (size_t)D_ * D_;      // WprojT elems

    u16* qkv = (u16*)d_ws;
    u16* Qp  = qkv;
    u16* Kp  = qkv + (size_t)HEADELEMS;
    u16* Vtp = qkv + (size_t)2 * HEADELEMS;

    const bool huge = ws_size >= ((size_t)3 * HEADELEMS + Y1E + WPE) * 2;
    const bool big  = ws_size >= ((size_t)3 * HEADELEMS + Y1E) * 2;

    u16* y1b    = big ? qkv + (size_t)3 * HEADELEMS : scratch;
    u16* y1g    = big ? y1b : Vtp;
    u16* WprojT = huge ? qkv + (size_t)3 * HEADELEMS + Y1E : Kp;

    // 1) fused prep
    prep_kernel<<<huge ? 5120 : 4864, 256, 0, stream>>>(
        x, Wqkv, Wproj, xb, WqkvT, WprojT);

    // 2) QKV GEMM -> Q(prescaled) | K | VT (bf16) in ws; 2D grid, pipelined
    gemm_mfma<1><<<dim3(3*D_/128, MROWS/128), 256, 0, stream>>>(
        xb, WqkvT, bqkv, (void*)qkv, MROWS, 3*D_, D_);

    // 3) attention -> y1 bf16; grid (hb=32, y=32), 64 q-rows/block
    attn_mfma_kernel<<<dim3(NH_*B_, T_/64), 256, 0, stream>>>(Qp, Kp, Vtp, y1b);

    // 4) Wproj transpose (non-huge paths; K dead now)
    if (!huge)
        transpose_conv_kernel<<<dim3(D_/64, D_/64), 256, 0, stream>>>(
            Wproj, WprojT, D_, D_);

    // 5) small-ws fallback: move y1 out of d_out
    if (!big)
        (void)hipMemcpyAsync(y1g, y1b, Y1E * sizeof(u16),
                             hipMemcpyDeviceToDevice, stream);

    // 6) output projection -> fp32 d_out; 2D grid
    gemm_mfma<0><<<dim3(D_/128, MROWS/128), 256, 0, stream>>>(
        y1g, WprojT, bproj, d_out, MROWS, D_, D_);
}

// Round 13
// 189.193 us; speedup vs baseline: 1.0281x; 1.0120x over previous
//
#include <hip/hip_runtime.h>
#include <hip/hip_bf16.h>

// Problem constants
#define B_   2
#define T_   2048
#define D_   1024
#define NH_  16
#define HD_  64
#define MROWS (B_*T_)              // 4096
#define HEADELEMS (B_*NH_*T_*HD_)  // 4194304 per Q/K/V tensor

// exp(s/8) = 2^(s * 0.125 * log2 e); folded into Q at the QKV epilogue
#define QSCALE 0.180336880f

typedef unsigned short u16;
typedef unsigned int   u32;

typedef float f32x4  __attribute__((ext_vector_type(4)));
typedef short bf16x8 __attribute__((ext_vector_type(8)));

// async global->LDS, 16 B/lane; LDS dest MUST be wave-uniform (base+lane*16)
#define GLP(g, l) __builtin_amdgcn_global_load_lds(                         \
    (const __attribute__((address_space(1))) void*)(g),                     \
    (__attribute__((address_space(3))) void*)(l), 16, 0, 0)

struct Fc { static constexpr bool value = false; };
struct Tc { static constexpr bool value = true;  };

__device__ __forceinline__ u16 f2bf(float f) {
    u32 x = __float_as_uint(f);
    u32 r = (x + 0x7fffu + ((x >> 16) & 1u)) >> 16;
    return (u16)r;
}
// packed fp32x2 -> bf16x2
__device__ __forceinline__ u32 pkbf2(float a, float b) {
    __hip_bfloat162 h = __float22bfloat162_rn(make_float2(a, b));
    union { __hip_bfloat162 h2; u32 u; } cv; cv.h2 = h; return cv.u;
}

// ---------------------------------------------------------------------------
// Fused prep: [0,4096) x fp32->bf16; [4096,4864) Wqkv -> bf16 T;
// [4864,5120) Wproj -> bf16 T (only launched on the huge-ws path).
// ---------------------------------------------------------------------------
__device__ __forceinline__ void transpose_tile(const float* in, u16* out,
                                               int K, int N, int bx, int by,
                                               int t, float (*Ts)[65])
{
    const int n0 = bx * 64;
    const int k0 = by * 64;
    #pragma unroll
    for (int pass = 0; pass < 4; pass++) {
        const int r = pass * 16 + (t >> 4);
        const int c = (t & 15) * 4;
        float4 v = *(const float4*)(in + (size_t)(k0 + r) * N + n0 + c);
        Ts[r][c] = v.x; Ts[r][c+1] = v.y; Ts[r][c+2] = v.z; Ts[r][c+3] = v.w;
    }
    __syncthreads();
    #pragma unroll
    for (int pass = 0; pass < 2; pass++) {
        const int nn = pass * 32 + (t >> 3);
        const int kk = (t & 7) * 8;
        u16 o[8];
        #pragma unroll
        for (int j = 0; j < 8; j++) o[j] = f2bf(Ts[kk + j][nn]);
        *(uint4*)(out + (size_t)(n0 + nn) * K + k0 + kk) = *(const uint4*)o;
    }
}

__global__ __launch_bounds__(256)
void prep_kernel(const float* __restrict__ x, const float* __restrict__ Wqkv,
                 const float* __restrict__ Wproj, u16* __restrict__ xb,
                 u16* __restrict__ WqkvT, u16* __restrict__ WprojT)
{
    __shared__ float Ts[64][65];
    const int bid = blockIdx.x;
    const int t   = threadIdx.x;
    if (bid < 4096) {
        int i = bid * 256 + t;
        float4 v = ((const float4*)x)[i];
        ushort4 o;
        o.x = f2bf(v.x); o.y = f2bf(v.y); o.z = f2bf(v.z); o.w = f2bf(v.w);
        ((ushort4*)xb)[i] = o;
    } else if (bid < 4096 + 768) {
        int tb = bid - 4096;                   // [3072][1024] T
        transpose_tile(Wqkv, WqkvT, D_, 3*D_, tb % 48, tb / 48, t, Ts);
    } else {
        int tb = bid - 4864;                   // [1024][1024] T
        transpose_tile(Wproj, WprojT, D_, D_, tb % 16, tb / 16, t, Ts);
    }
}

__global__ __launch_bounds__(256)
void transpose_conv_kernel(const float* __restrict__ in, u16* __restrict__ out,
                           int K, int N)
{
    __shared__ float Ts[64][65];
    transpose_tile(in, out, K, N, blockIdx.x, blockIdx.y, threadIdx.x, Ts);
}

// ---------------------------------------------------------------------------
// MFMA GEMM (r10 config, VERIFIED BEST — do not touch): counted-vmcnt
// double-buffered pipeline on 128x128 / 4-wave / BK=64, 2D grid (proven L2
// pattern). Per K-step: STAGE(buf^1, k+1) -> vmcnt(8) -> s_barrier ->
// ds_read + 32 MFMA -> lgkmcnt(0) + s_barrier. Never drains vmcnt to 0
// in-loop. Staging: per-lane global row srow=t>>3, pre-swizzled seg
// ((t&7)^(srow&7)); wave-uniform LDS base wave*8 (+32/64/96). Frag read
// col (quad^(l16&7))*8 ^ (kk*32). Conflicts = 0 (r9/r10-verified).
// MODE 0: fp32 row-major + bias. MODE 1: scatter bf16 Q(*QSCALE),K | V^T.
// ---------------------------------------------------------------------------
template <int MODE>
__global__ __launch_bounds__(256)
void gemm_mfma(const u16* __restrict__ A, const u16* __restrict__ BT,
               const float* __restrict__ bias, void* __restrict__ outv,
               int M, int N, int K)
{
    __shared__ u16 As[2][128][64];
    __shared__ u16 Bs[2][128][64];

    const int t    = threadIdx.x;
    const int wave = t >> 6;
    const int lane = t & 63;
    const int l16  = lane & 15;
    const int quad = lane >> 4;

    const int m0 = blockIdx.y * 128;
    const int n0 = blockIdx.x * 128;
    const int mb = (wave >> 1) * 64;
    const int nb = (wave & 1) * 64;

    const int srow = t >> 3;                     // 0..31 (block-wide)
    const int sseg = ((t & 7) ^ (srow & 7)) * 8; // pre-swizzled k-offset
    const int rw8  = wave * 8;                   // wave-uniform LDS row base

    const u16* gA = A  + (size_t)(m0 + srow) * K + sseg;
    const u16* gB = BT + (size_t)(n0 + srow) * K + sseg;

    const int fragcol = (quad ^ (l16 & 7)) * 8;

    f32x4 acc[4][4];
    #pragma unroll
    for (int i = 0; i < 4; i++)
        #pragma unroll
        for (int j = 0; j < 4; j++) acc[i][j] = (f32x4){0,0,0,0};

    auto STAGE = [&](int buf, int k0) {
        GLP(gA + k0,          &As[buf][rw8     ][0]);
        GLP(gA + k0 + 32*K,   &As[buf][rw8 + 32][0]);
        GLP(gA + k0 + 64*K,   &As[buf][rw8 + 64][0]);
        GLP(gA + k0 + 96*K,   &As[buf][rw8 + 96][0]);
        GLP(gB + k0,          &Bs[buf][rw8     ][0]);
        GLP(gB + k0 + 32*K,   &Bs[buf][rw8 + 32][0]);
        GLP(gB + k0 + 64*K,   &Bs[buf][rw8 + 64][0]);
        GLP(gB + k0 + 96*K,   &Bs[buf][rw8 + 96][0]);
    };

    const int nk = K >> 6;

    STAGE(0, 0);
    asm volatile("s_waitcnt vmcnt(0)" ::: "memory");
    __builtin_amdgcn_s_barrier();

    for (int kt = 0; kt < nk; ++kt) {
        const int cur = kt & 1;
        const bool have_next = (kt + 1 < nk);

        if (have_next) {
            STAGE(cur ^ 1, (kt + 1) << 6);
            asm volatile("s_waitcnt vmcnt(8)" ::: "memory");
        } else {
            asm volatile("s_waitcnt vmcnt(0)" ::: "memory");
        }
        __builtin_amdgcn_s_barrier();

        #pragma unroll
        for (int kk = 0; kk < 2; kk++) {
            const int fc = fragcol ^ (kk << 5);
            bf16x8 af[4], bfr[4];
            #pragma unroll
            for (int i = 0; i < 4; i++)
                af[i] = *(const bf16x8*)&As[cur][mb + i*16 + l16][fc];
            #pragma unroll
            for (int j = 0; j < 4; j++)
                bfr[j] = *(const bf16x8*)&Bs[cur][nb + j*16 + l16][fc];

            #pragma unroll
            for (int i = 0; i < 4; i++)
                #pragma unroll
                for (int j = 0; j < 4; j++)
                    acc[i][j] = __builtin_amdgcn_mfma_f32_16x16x32_bf16(
                        af[i], bfr[j], acc[i][j], 0, 0, 0);
        }

        if (have_next) {
            asm volatile("s_waitcnt lgkmcnt(0)" ::: "memory");
            __builtin_amdgcn_s_barrier();
        }
    }

    if (MODE == 0) {
        #pragma unroll
        for (int j = 0; j < 4; j++) {
            const int n = n0 + nb + j*16 + l16;
            const float bv = bias[n];
            #pragma unroll
            for (int i = 0; i < 4; i++) {
                #pragma unroll
                for (int r = 0; r < 4; r++) {
                    const int m = m0 + mb + i*16 + quad*4 + r;
                    ((float*)outv)[(size_t)m * N + n] = acc[i][j][r] + bv;
                }
            }
        }
    } else {
        const int sec = n0 >> 10;        // block-uniform: 0=q 1=k 2=v
        const int b   = m0 >> 11;        // block-uniform batch index
        const int tb  = m0 & 2047;
        if (sec < 2) {
            const float qs = (sec == 0) ? QSCALE : 1.f;
            #pragma unroll
            for (int j = 0; j < 4; j++) {
                const int n  = n0 + nb + j*16 + l16;
                const float bv = bias[n];
                const int dd = n & 1023;
                const int h  = dd >> 6;
                const int hd = dd & 63;
                u16* op = (u16*)outv + (size_t)sec * HEADELEMS
                        + ((size_t)(b*NH_ + h)) * T_ * HD_ + hd;
                #pragma unroll
                for (int i = 0; i < 4; i++) {
                    #pragma unroll
                    for (int r = 0; r < 4; r++) {
                        const int tt = tb + mb + i*16 + quad*4 + r;
                        op[(size_t)tt * HD_] = f2bf((acc[i][j][r] + bv) * qs);
                    }
                }
            }
        } else {
            #pragma unroll
            for (int j = 0; j < 4; j++) {
                const int n  = n0 + nb + j*16 + l16;
                const float bv = bias[n];
                const int dd = n & 1023;
                const int h  = dd >> 6;
                const int hd = dd & 63;
                u16* vp = (u16*)outv + (size_t)2 * HEADELEMS
                        + ((size_t)(b*NH_ + h)) * T_ * HD_
                        + (size_t)hd * T_ + tb + mb;
                #pragma unroll
                for (int i = 0; i < 4; i++) {
                    u16 o[4];
                    #pragma unroll
                    for (int r = 0; r < 4; r++) o[r] = f2bf(acc[i][j][r] + bv);
                    *(uint2*)(vp + i*16 + quad*4) = *(const uint2*)o;
                }
            }
        }
    }
}

// ---------------------------------------------------------------------------
// MFMA flash attention v10. Round-21: r10 staging RESTORED (reg-roundtrip
// loads issued before compute, ds_writes after — the implicit T14 split
// that beat r12's GLP version), ONE change vs r10: all 8 V-fragment
// ds_read_b128s hoisted BEFORE the 16-bpermute shuffle block, so the LDS
// pipe overlaps V reads with bpermute latency instead of serializing
// read-after-shuffle, and the PV MFMA cluster fires the moment pf lands.
// Everything else r10-exact: [64][64] XOR-seg layout (conflict-free),
// balanced yy->qt mapping (62 tiles/CU), T5 setprio, ones-MFMA row sums,
// compile-time masked-tile split.
// ---------------------------------------------------------------------------
__global__ __launch_bounds__(256)
void attn_mfma_kernel(const u16* __restrict__ Q, const u16* __restrict__ K,
                      const u16* __restrict__ VT, u16* __restrict__ y1)
{
    __shared__ u16 Ks[2][64][64];     // [buf][key][d]   (XOR-seg swizzled)
    __shared__ u16 Vs[2][64][64];     // [buf][d][key]   (XOR-seg swizzled)

    const int t    = threadIdx.x;
    const int wave = t >> 6;
    const int lane = t & 63;
    const int l16  = lane & 15;
    const int quad = lane >> 4;

    const int hb = blockIdx.x;                 // b*NH + h (XCD-pinned)
    const int yy = blockIdx.y;
    const int a  = yy & 7, g = yy >> 3;
    const int qt = (g == 0) ? 31 - a : (g == 1) ? 16 + a
                 : (g == 2) ? 15 - a : a;      // balanced 4-way pairing
    const int b  = hb >> 4;
    const int h  = hb & 15;
    const size_t base = (size_t)hb * T_ * HD_;

    const int qw0 = qt * 64 + wave * 16;       // first q-row of this wave

    // Q fragment: 2 d-chunks (Q pre-scaled by QSCALE)
    bf16x8 qf[2];
    {
        const u16* qp = Q + base + (size_t)(qw0 + l16) * HD_ + quad * 8;
        qf[0] = *(const bf16x8*)(qp);
        qf[1] = *(const bf16x8*)(qp + 32);
    }

    bf16x8 onesf;
    #pragma unroll
    for (int i = 0; i < 8; i++) onesf[i] = (short)0x3F80;

    f32x4 o[4];
    #pragma unroll
    for (int d = 0; d < 4; d++) o[d] = (f32x4){0,0,0,0};
    f32x4 accl = (f32x4){0,0,0,0};

    const int nsteps = qt + 1;                 // uniform across waves

    const int srow = t >> 3;                   // 0..31
    const int scol = (t & 7) * 8;              // logical seg * 8
    const int sst  = (((t & 7) ^ (srow & 7)) * 8);  // stored (swizzled) col

    // fragment-read swizzled columns
    const int fs0 = (quad ^ (l16 & 7)) * 8;
    const int fs1 = fs0 ^ 32;

    // shuffle sources for C->A redistribution (r10-verified)
    const int srcA  = l16 + ((quad & 1) << 5);
    const int srcB  = srcA + 16;
    const bool selhi = (quad >> 1) != 0;

    // stage tile 0
    uint4 kr0, kr1, vr0, vr1;
    {
        const u16* kp = K + base + (size_t)srow * HD_ + scol;
        kr0 = *(const uint4*)kp;
        kr1 = *(const uint4*)(kp + 32 * HD_);
        const u16* vp = VT + base + (size_t)srow * T_ + scol;
        vr0 = *(const uint4*)vp;
        vr1 = *(const uint4*)(vp + 32 * T_);
        *(uint4*)&Ks[0][srow][sst]      = kr0;
        *(uint4*)&Ks[0][srow + 32][sst] = kr1;
        *(uint4*)&Vs[0][srow][sst]      = vr0;
        *(uint4*)&Vs[0][srow + 32][sst] = vr1;
    }
    __syncthreads();

    auto compute_tile = [&](int cur, int k0, auto mc) {
        constexpr bool MASKED = decltype(mc)::value;
        // S^T = K_tile . Q^T
        f32x4 st[4];
        __builtin_amdgcn_s_setprio(1);
        #pragma unroll
        for (int j = 0; j < 4; j++) {
            bf16x8 kf0 = *(const bf16x8*)&Ks[cur][j*16 + l16][fs0];
            bf16x8 kf1 = *(const bf16x8*)&Ks[cur][j*16 + l16][fs1];
            f32x4 z = {0,0,0,0};
            z = __builtin_amdgcn_mfma_f32_16x16x32_bf16(kf0, qf[0], z, 0, 0, 0);
            st[j] = __builtin_amdgcn_mfma_f32_16x16x32_bf16(kf1, qf[1], z, 0, 0, 0);
        }
        __builtin_amdgcn_s_setprio(0);

        // V fragments hoisted: independent of pf -> LDS pipe overlaps these
        // 8 ds_read_b128 with the bpermute chain below
        bf16x8 vf0[4], vf1[4];
        #pragma unroll
        for (int d = 0; d < 4; d++) {
            vf0[d] = *(const bf16x8*)&Vs[cur][d*16 + l16][fs0];
            vf1[d] = *(const bf16x8*)&Vs[cur][d*16 + l16][fs1];
        }

        // exp2 (+ mask, compile-time gated) + packed bf16
        u32 p01[4], p23[4];
        const int qi = qw0 + l16;
        #pragma unroll
        for (int j = 0; j < 4; j++) {
            const int kb = k0 + j*16 + quad*4;
            float e0 = __builtin_amdgcn_exp2f(st[j][0]);
            float e1 = __builtin_amdgcn_exp2f(st[j][1]);
            float e2 = __builtin_amdgcn_exp2f(st[j][2]);
            float e3 = __builtin_amdgcn_exp2f(st[j][3]);
            if (MASKED) {
                if (kb + 0 > qi) e0 = 0.f;
                if (kb + 1 > qi) e1 = 0.f;
                if (kb + 2 > qi) e2 = 0.f;
                if (kb + 3 > qi) e3 = 0.f;
            }
            p01[j] = pkbf2(e0, e1);
            p23[j] = pkbf2(e2, e3);
        }

        // C->A redistribution via shuffles; then ones-MFMA + PV
        bf16x8 pf[2];
        #pragma unroll
        for (int c = 0; c < 2; c++) {
            u32 t0, t1, r01, r23, r45, r67;
            t0 = (u32)__shfl((int)p01[2*c],   srcA);
            t1 = (u32)__shfl((int)p01[2*c+1], srcA);
            r01 = selhi ? t1 : t0;
            t0 = (u32)__shfl((int)p23[2*c],   srcA);
            t1 = (u32)__shfl((int)p23[2*c+1], srcA);
            r23 = selhi ? t1 : t0;
            t0 = (u32)__shfl((int)p01[2*c],   srcB);
            t1 = (u32)__shfl((int)p01[2*c+1], srcB);
            r45 = selhi ? t1 : t0;
            t0 = (u32)__shfl((int)p23[2*c],   srcB);
            t1 = (u32)__shfl((int)p23[2*c+1], srcB);
            r67 = selhi ? t1 : t0;
            union { u32 u[4]; bf16x8 v; } pk;
            pk.u[0] = r01; pk.u[1] = r23; pk.u[2] = r45; pk.u[3] = r67;
            pf[c] = pk.v;
        }
        __builtin_amdgcn_s_setprio(1);
        accl = __builtin_amdgcn_mfma_f32_16x16x32_bf16(pf[0], onesf, accl, 0, 0, 0);
        accl = __builtin_amdgcn_mfma_f32_16x16x32_bf16(pf[1], onesf, accl, 0, 0, 0);
        #pragma unroll
        for (int d = 0; d < 4; d++) {
            o[d] = __builtin_amdgcn_mfma_f32_16x16x32_bf16(pf[0], vf0[d], o[d], 0, 0, 0);
            o[d] = __builtin_amdgcn_mfma_f32_16x16x32_bf16(pf[1], vf1[d], o[d], 0, 0, 0);
        }
        __builtin_amdgcn_s_setprio(0);
    };

    for (int kt = 0; kt < nsteps; kt++) {
        const int cur = kt & 1;
        const int k0  = kt * 64;
        const bool have_next = (kt + 1 < nsteps);

        if (have_next) {
            const u16* kp = K + base + (size_t)(k0 + 64 + srow) * HD_ + scol;
            kr0 = *(const uint4*)kp;
            kr1 = *(const uint4*)(kp + 32 * HD_);
            const u16* vp = VT + base + (size_t)srow * T_ + k0 + 64 + scol;
            vr0 = *(const uint4*)vp;
            vr1 = *(const uint4*)(vp + 32 * T_);
        }

        if (kt < qt) compute_tile(cur, k0, Fc{});
        else         compute_tile(cur, k0, Tc{});

        if (have_next) {
            const int nxt = cur ^ 1;
            *(uint4*)&Ks[nxt][srow][sst]      = kr0;
            *(uint4*)&Ks[nxt][srow + 32][sst] = kr1;
            *(uint4*)&Vs[nxt][srow][sst]      = vr0;
            *(uint4*)&Vs[nxt][srow + 32][sst] = vr1;
            __syncthreads();
        }
    }

    // epilogue: normalize by ones-MFMA row sums; y1[B,T,D] bf16
    #pragma unroll
    for (int r = 0; r < 4; r++) {
        const float inv = 1.f / accl[r];
        const int qi = qw0 + quad*4 + r;
        u16* yp = y1 + ((size_t)(b * T_ + qi)) * D_ + h * HD_ + l16;
        yp[0]  = f2bf(o[0][r] * inv);
        yp[16] = f2bf(o[1][r] * inv);
        yp[32] = f2bf(o[2][r] * inv);
        yp[48] = f2bf(o[3][r] * inv);
    }
}

// ---------------------------------------------------------------------------
// Choreography, three ws tiers:
//  huge (>= 3*QKV + y1 + WprojT = ~35.7 MB): prep also transposes Wproj into
//    ws; attn -> y1 in ws; 4 dispatches, no memcpy.
//  big  (>= 3*QKV + y1 = ~33.5 MB): y1 in ws; WprojT over dead K after attn.
//  small: y1 over dead xb in d_out; memcpy to dead VT; WprojT over dead K.
// ---------------------------------------------------------------------------
extern "C" void kernel_launch(void* const* d_in, const int* in_sizes, int n_in,
                              void* d_out, int out_size, void* d_ws, size_t ws_size,
                              hipStream_t stream)
{
    const float* x     = (const float*)d_in[0];
    const float* Wqkv  = (const float*)d_in[1];
    const float* bqkv  = (const float*)d_in[2];
    const float* Wproj = (const float*)d_in[3];
    const float* bproj = (const float*)d_in[4];

    u16* scratch = (u16*)d_out;
    u16* xb      = scratch;
    u16* WqkvT   = scratch + (size_t)MROWS * D_;

    const size_t Y1E = (size_t)MROWS * D_;   // y1 elems (== HEADELEMS)
    const size_t WPE = (size_t)D_ * D_;      // WprojT elems

    u16* qkv = (u16*)d_ws;
    u16* Qp  = qkv;
    u16* Kp  = qkv + (size_t)HEADELEMS;
    u16* Vtp = qkv + (size_t)2 * HEADELEMS;

    const bool huge = ws_size >= ((size_t)3 * HEADELEMS + Y1E + WPE) * 2;
    const bool big  = ws_size >= ((size_t)3 * HEADELEMS + Y1E) * 2;

    u16* y1b    = big ? qkv + (size_t)3 * HEADELEMS : scratch;
    u16* y1g    = big ? y1b : Vtp;
    u16* WprojT = huge ? qkv + (size_t)3 * HEADELEMS + Y1E : Kp;

    // 1) fused prep
    prep_kernel<<<huge ? 5120 : 4864, 256, 0, stream>>>(
        x, Wqkv, Wproj, xb, WqkvT, WprojT);

    // 2) QKV GEMM -> Q(prescaled) | K | VT (bf16) in ws; 2D grid, pipelined
    gemm_mfma<1><<<dim3(3*D_/128, MROWS/128), 256, 0, stream>>>(
        xb, WqkvT, bqkv, (void*)qkv, MROWS, 3*D_, D_);

    // 3) attention -> y1 bf16; grid (hb=32, y=32), 64 q-rows/block
    attn_mfma_kernel<<<dim3(NH_*B_, T_/64), 256, 0, stream>>>(Qp, Kp, Vtp, y1b);

    // 4) Wproj transpose (non-huge paths; K dead now)
    if (!huge)
        transpose_conv_kernel<<<dim3(D_/64, D_/64), 256, 0, stream>>>(
            Wproj, WprojT, D_, D_);

    // 5) small-ws fallback: move y1 out of d_out
    if (!big)
        (void)hipMemcpyAsync(y1g, y1b, Y1E * sizeof(u16),
                             hipMemcpyDeviceToDevice, stream);

    // 6) output projection -> fp32 d_out; 2D grid
    gemm_mfma<0><<<dim3(D_/128, MROWS/128), 256, 0, stream>>>(
        y1g, WprojT, bproj, d_out, MROWS, D_, D_);
}

// Round 14
// 187.195 us; speedup vs baseline: 1.0391x; 1.0107x over previous
//
#include <hip/hip_runtime.h>
#include <hip/hip_bf16.h>

// Problem constants
#define B_   2
#define T_   2048
#define D_   1024
#define NH_  16
#define HD_  64
#define MROWS (B_*T_)              // 4096
#define HEADELEMS (B_*NH_*T_*HD_)  // 4194304 per Q/K/V tensor

// exp(s/8) = 2^(s * 0.125 * log2 e); folded into Q at the QKV epilogue
#define QSCALE 0.180336880f

typedef unsigned short u16;
typedef unsigned int   u32;

typedef float f32x4  __attribute__((ext_vector_type(4)));
typedef short bf16x8 __attribute__((ext_vector_type(8)));

// async global->LDS, 16 B/lane; LDS dest MUST be wave-uniform (base+lane*16)
#define GLP(g, l) __builtin_amdgcn_global_load_lds(                         \
    (const __attribute__((address_space(1))) void*)(g),                     \
    (__attribute__((address_space(3))) void*)(l), 16, 0, 0)

struct Fc { static constexpr bool value = false; };
struct Tc { static constexpr bool value = true;  };

__device__ __forceinline__ u16 f2bf(float f) {
    u32 x = __float_as_uint(f);
    u32 r = (x + 0x7fffu + ((x >> 16) & 1u)) >> 16;
    return (u16)r;
}
// packed fp32x2 -> bf16x2
__device__ __forceinline__ u32 pkbf2(float a, float b) {
    __hip_bfloat162 h = __float22bfloat162_rn(make_float2(a, b));
    union { __hip_bfloat162 h2; u32 u; } cv; cv.h2 = h; return cv.u;
}

// ---------------------------------------------------------------------------
// Fused prep: [0,4096) x fp32->bf16; [4096,4864) Wqkv -> bf16 T;
// [4864,5120) Wproj -> bf16 T (only launched on the huge-ws path).
// ---------------------------------------------------------------------------
__device__ __forceinline__ void transpose_tile(const float* in, u16* out,
                                               int K, int N, int bx, int by,
                                               int t, float (*Ts)[65])
{
    const int n0 = bx * 64;
    const int k0 = by * 64;
    #pragma unroll
    for (int pass = 0; pass < 4; pass++) {
        const int r = pass * 16 + (t >> 4);
        const int c = (t & 15) * 4;
        float4 v = *(const float4*)(in + (size_t)(k0 + r) * N + n0 + c);
        Ts[r][c] = v.x; Ts[r][c+1] = v.y; Ts[r][c+2] = v.z; Ts[r][c+3] = v.w;
    }
    __syncthreads();
    #pragma unroll
    for (int pass = 0; pass < 2; pass++) {
        const int nn = pass * 32 + (t >> 3);
        const int kk = (t & 7) * 8;
        u16 o[8];
        #pragma unroll
        for (int j = 0; j < 8; j++) o[j] = f2bf(Ts[kk + j][nn]);
        *(uint4*)(out + (size_t)(n0 + nn) * K + k0 + kk) = *(const uint4*)o;
    }
}

__global__ __launch_bounds__(256)
void prep_kernel(const float* __restrict__ x, const float* __restrict__ Wqkv,
                 const float* __restrict__ Wproj, u16* __restrict__ xb,
                 u16* __restrict__ WqkvT, u16* __restrict__ WprojT)
{
    __shared__ float Ts[64][65];
    const int bid = blockIdx.x;
    const int t   = threadIdx.x;
    if (bid < 4096) {
        int i = bid * 256 + t;
        float4 v = ((const float4*)x)[i];
        ushort4 o;
        o.x = f2bf(v.x); o.y = f2bf(v.y); o.z = f2bf(v.z); o.w = f2bf(v.w);
        ((ushort4*)xb)[i] = o;
    } else if (bid < 4096 + 768) {
        int tb = bid - 4096;                   // [3072][1024] T
        transpose_tile(Wqkv, WqkvT, D_, 3*D_, tb % 48, tb / 48, t, Ts);
    } else {
        int tb = bid - 4864;                   // [1024][1024] T
        transpose_tile(Wproj, WprojT, D_, D_, tb % 16, tb / 16, t, Ts);
    }
}

__global__ __launch_bounds__(256)
void transpose_conv_kernel(const float* __restrict__ in, u16* __restrict__ out,
                           int K, int N)
{
    __shared__ float Ts[64][65];
    transpose_tile(in, out, K, N, blockIdx.x, blockIdx.y, threadIdx.x, Ts);
}

// ---------------------------------------------------------------------------
// MFMA GEMM (r10 config, VERIFIED BEST — do not touch): counted-vmcnt
// double-buffered pipeline on 128x128 / 4-wave / BK=64, 2D grid (proven L2
// pattern). Per K-step: STAGE(buf^1, k+1) -> vmcnt(8) -> s_barrier ->
// ds_read + 32 MFMA -> lgkmcnt(0) + s_barrier. Never drains vmcnt to 0
// in-loop. Staging: per-lane global row srow=t>>3, pre-swizzled seg
// ((t&7)^(srow&7)); wave-uniform LDS base wave*8 (+32/64/96). Frag read
// col (quad^(l16&7))*8 ^ (kk*32). Conflicts = 0 (r9/r10-verified).
// MODE 0: fp32 row-major + bias. MODE 1: scatter bf16 Q(*QSCALE),K | V^T.
// ---------------------------------------------------------------------------
template <int MODE>
__global__ __launch_bounds__(256)
void gemm_mfma(const u16* __restrict__ A, const u16* __restrict__ BT,
               const float* __restrict__ bias, void* __restrict__ outv,
               int M, int N, int K)
{
    __shared__ u16 As[2][128][64];
    __shared__ u16 Bs[2][128][64];

    const int t    = threadIdx.x;
    const int wave = t >> 6;
    const int lane = t & 63;
    const int l16  = lane & 15;
    const int quad = lane >> 4;

    const int m0 = blockIdx.y * 128;
    const int n0 = blockIdx.x * 128;
    const int mb = (wave >> 1) * 64;
    const int nb = (wave & 1) * 64;

    const int srow = t >> 3;                     // 0..31 (block-wide)
    const int sseg = ((t & 7) ^ (srow & 7)) * 8; // pre-swizzled k-offset
    const int rw8  = wave * 8;                   // wave-uniform LDS row base

    const u16* gA = A  + (size_t)(m0 + srow) * K + sseg;
    const u16* gB = BT + (size_t)(n0 + srow) * K + sseg;

    const int fragcol = (quad ^ (l16 & 7)) * 8;

    f32x4 acc[4][4];
    #pragma unroll
    for (int i = 0; i < 4; i++)
        #pragma unroll
        for (int j = 0; j < 4; j++) acc[i][j] = (f32x4){0,0,0,0};

    auto STAGE = [&](int buf, int k0) {
        GLP(gA + k0,          &As[buf][rw8     ][0]);
        GLP(gA + k0 + 32*K,   &As[buf][rw8 + 32][0]);
        GLP(gA + k0 + 64*K,   &As[buf][rw8 + 64][0]);
        GLP(gA + k0 + 96*K,   &As[buf][rw8 + 96][0]);
        GLP(gB + k0,          &Bs[buf][rw8     ][0]);
        GLP(gB + k0 + 32*K,   &Bs[buf][rw8 + 32][0]);
        GLP(gB + k0 + 64*K,   &Bs[buf][rw8 + 64][0]);
        GLP(gB + k0 + 96*K,   &Bs[buf][rw8 + 96][0]);
    };

    const int nk = K >> 6;

    STAGE(0, 0);
    asm volatile("s_waitcnt vmcnt(0)" ::: "memory");
    __builtin_amdgcn_s_barrier();

    for (int kt = 0; kt < nk; ++kt) {
        const int cur = kt & 1;
        const bool have_next = (kt + 1 < nk);

        if (have_next) {
            STAGE(cur ^ 1, (kt + 1) << 6);
            asm volatile("s_waitcnt vmcnt(8)" ::: "memory");
        } else {
            asm volatile("s_waitcnt vmcnt(0)" ::: "memory");
        }
        __builtin_amdgcn_s_barrier();

        #pragma unroll
        for (int kk = 0; kk < 2; kk++) {
            const int fc = fragcol ^ (kk << 5);
            bf16x8 af[4], bfr[4];
            #pragma unroll
            for (int i = 0; i < 4; i++)
                af[i] = *(const bf16x8*)&As[cur][mb + i*16 + l16][fc];
            #pragma unroll
            for (int j = 0; j < 4; j++)
                bfr[j] = *(const bf16x8*)&Bs[cur][nb + j*16 + l16][fc];

            #pragma unroll
            for (int i = 0; i < 4; i++)
                #pragma unroll
                for (int j = 0; j < 4; j++)
                    acc[i][j] = __builtin_amdgcn_mfma_f32_16x16x32_bf16(
                        af[i], bfr[j], acc[i][j], 0, 0, 0);
        }

        if (have_next) {
            asm volatile("s_waitcnt lgkmcnt(0)" ::: "memory");
            __builtin_amdgcn_s_barrier();
        }
    }

    if (MODE == 0) {
        #pragma unroll
        for (int j = 0; j < 4; j++) {
            const int n = n0 + nb + j*16 + l16;
            const float bv = bias[n];
            #pragma unroll
            for (int i = 0; i < 4; i++) {
                #pragma unroll
                for (int r = 0; r < 4; r++) {
                    const int m = m0 + mb + i*16 + quad*4 + r;
                    ((float*)outv)[(size_t)m * N + n] = acc[i][j][r] + bv;
                }
            }
        }
    } else {
        const int sec = n0 >> 10;        // block-uniform: 0=q 1=k 2=v
        const int b   = m0 >> 11;        // block-uniform batch index
        const int tb  = m0 & 2047;
        if (sec < 2) {
            const float qs = (sec == 0) ? QSCALE : 1.f;
            #pragma unroll
            for (int j = 0; j < 4; j++) {
                const int n  = n0 + nb + j*16 + l16;
                const float bv = bias[n];
                const int dd = n & 1023;
                const int h  = dd >> 6;
                const int hd = dd & 63;
                u16* op = (u16*)outv + (size_t)sec * HEADELEMS
                        + ((size_t)(b*NH_ + h)) * T_ * HD_ + hd;
                #pragma unroll
                for (int i = 0; i < 4; i++) {
                    #pragma unroll
                    for (int r = 0; r < 4; r++) {
                        const int tt = tb + mb + i*16 + quad*4 + r;
                        op[(size_t)tt * HD_] = f2bf((acc[i][j][r] + bv) * qs);
                    }
                }
            }
        } else {
            #pragma unroll
            for (int j = 0; j < 4; j++) {
                const int n  = n0 + nb + j*16 + l16;
                const float bv = bias[n];
                const int dd = n & 1023;
                const int h  = dd >> 6;
                const int hd = dd & 63;
                u16* vp = (u16*)outv + (size_t)2 * HEADELEMS
                        + ((size_t)(b*NH_ + h)) * T_ * HD_
                        + (size_t)hd * T_ + tb + mb;
                #pragma unroll
                for (int i = 0; i < 4; i++) {
                    u16 o[4];
                    #pragma unroll
                    for (int r = 0; r < 4; r++) o[r] = f2bf(acc[i][j][r] + bv);
                    *(uint2*)(vp + i*16 + quad*4) = *(const uint2*)o;
                }
            }
        }
    }
}

// ---------------------------------------------------------------------------
// Round-22: proj-only GEMM, 64x128 tile / 2-wave / BK=64 with the SAME
// counted-vmcnt pipeline. Rationale: proj's 128^2 grid = 256 blocks =
// 1 block/CU (worst regime on the m102 curve, ~320 TF). 64x128 doubles the
// grid to 512 = 2 blocks/CU; LDS 48 KB (A 8K + B 16K, x2 dbuf) permits 3.
// Per-wave: 12 GLPs (A rows wave*32+{0,8,16,24}, B rows wave*64+{0..56}),
// vmcnt(12); frag geometry/swizzle identical to the proven kernel
// (row&7 == l16&7 for both A and B reads). fp32 row-major + bias epilogue.
// ---------------------------------------------------------------------------
__global__ __launch_bounds__(128)
void gemm_mfma_64(const u16* __restrict__ A, const u16* __restrict__ BT,
                  const float* __restrict__ bias, float* __restrict__ out,
                  int M, int N, int K)
{
    __shared__ u16 As[2][64][64];
    __shared__ u16 Bs[2][128][64];

    const int t    = threadIdx.x;
    const int wave = t >> 6;           // 0..1
    const int lane = t & 63;
    const int l16  = lane & 15;
    const int quad = lane >> 4;

    const int m0 = blockIdx.y * 64;
    const int n0 = blockIdx.x * 128;
    const int nb = wave * 64;

    const int lrow = lane >> 3;                   // 0..7
    const int sseg = ((lane & 7) ^ lrow) * 8;     // pre-swizzled k-offset
    const int ra   = wave * 32;                   // A LDS row base
    const int rb   = wave * 64;                   // B LDS row base

    const u16* gA = A  + (size_t)(m0 + ra + lrow) * K + sseg;
    const u16* gB = BT + (size_t)(n0 + rb + lrow) * K + sseg;

    const int fragcol = (quad ^ (l16 & 7)) * 8;

    f32x4 acc[4][4];
    #pragma unroll
    for (int i = 0; i < 4; i++)
        #pragma unroll
        for (int j = 0; j < 4; j++) acc[i][j] = (f32x4){0,0,0,0};

    // per-wave 12 GLPs: 4 for A (32 rows), 8 for B (64 rows)
    auto STAGE = [&](int buf, int k0) {
        GLP(gA + k0,         &As[buf][ra     ][0]);
        GLP(gA + k0 +  8*K,  &As[buf][ra +  8][0]);
        GLP(gA + k0 + 16*K,  &As[buf][ra + 16][0]);
        GLP(gA + k0 + 24*K,  &As[buf][ra + 24][0]);
        GLP(gB + k0,         &Bs[buf][rb     ][0]);
        GLP(gB + k0 +  8*K,  &Bs[buf][rb +  8][0]);
        GLP(gB + k0 + 16*K,  &Bs[buf][rb + 16][0]);
        GLP(gB + k0 + 24*K,  &Bs[buf][rb + 24][0]);
        GLP(gB + k0 + 32*K,  &Bs[buf][rb + 32][0]);
        GLP(gB + k0 + 40*K,  &Bs[buf][rb + 40][0]);
        GLP(gB + k0 + 48*K,  &Bs[buf][rb + 48][0]);
        GLP(gB + k0 + 56*K,  &Bs[buf][rb + 56][0]);
    };

    const int nk = K >> 6;

    STAGE(0, 0);
    asm volatile("s_waitcnt vmcnt(0)" ::: "memory");
    __builtin_amdgcn_s_barrier();

    for (int kt = 0; kt < nk; ++kt) {
        const int cur = kt & 1;
        const bool have_next = (kt + 1 < nk);

        if (have_next) {
            STAGE(cur ^ 1, (kt + 1) << 6);
            asm volatile("s_waitcnt vmcnt(12)" ::: "memory");
        } else {
            asm volatile("s_waitcnt vmcnt(0)" ::: "memory");
        }
        __builtin_amdgcn_s_barrier();

        #pragma unroll
        for (int kk = 0; kk < 2; kk++) {
            const int fc = fragcol ^ (kk << 5);
            bf16x8 af[4], bfr[4];
            #pragma unroll
            for (int i = 0; i < 4; i++)
                af[i] = *(const bf16x8*)&As[cur][i*16 + l16][fc];
            #pragma unroll
            for (int j = 0; j < 4; j++)
                bfr[j] = *(const bf16x8*)&Bs[cur][nb + j*16 + l16][fc];

            #pragma unroll
            for (int i = 0; i < 4; i++)
                #pragma unroll
                for (int j = 0; j < 4; j++)
                    acc[i][j] = __builtin_amdgcn_mfma_f32_16x16x32_bf16(
                        af[i], bfr[j], acc[i][j], 0, 0, 0);
        }

        if (have_next) {
            asm volatile("s_waitcnt lgkmcnt(0)" ::: "memory");
            __builtin_amdgcn_s_barrier();
        }
    }

    #pragma unroll
    for (int j = 0; j < 4; j++) {
        const int n = n0 + nb + j*16 + l16;
        const float bv = bias[n];
        #pragma unroll
        for (int i = 0; i < 4; i++) {
            #pragma unroll
            for (int r = 0; r < 4; r++) {
                const int m = m0 + i*16 + quad*4 + r;
                out[(size_t)m * N + n] = acc[i][j][r] + bv;
            }
        }
    }
}

// ---------------------------------------------------------------------------
// MFMA flash attention v10 (r13 config, VERIFIED BEST): r10 reg-roundtrip
// staging (loads before compute, ds_writes after — implicit T14 split),
// V-fragment ds_reads hoisted before the bpermute chain, [64][64] XOR-seg
// layout (conflict-free), balanced yy->qt mapping (62 tiles/CU), T5
// setprio, ones-MFMA row sums, compile-time masked-tile split.
// ---------------------------------------------------------------------------
__global__ __launch_bounds__(256)
void attn_mfma_kernel(const u16* __restrict__ Q, const u16* __restrict__ K,
                      const u16* __restrict__ VT, u16* __restrict__ y1)
{
    __shared__ u16 Ks[2][64][64];     // [buf][key][d]   (XOR-seg swizzled)
    __shared__ u16 Vs[2][64][64];     // [buf][d][key]   (XOR-seg swizzled)

    const int t    = threadIdx.x;
    const int wave = t >> 6;
    const int lane = t & 63;
    const int l16  = lane & 15;
    const int quad = lane >> 4;

    const int hb = blockIdx.x;                 // b*NH + h (XCD-pinned)
    const int yy = blockIdx.y;
    const int a  = yy & 7, g = yy >> 3;
    const int qt = (g == 0) ? 31 - a : (g == 1) ? 16 + a
                 : (g == 2) ? 15 - a : a;      // balanced 4-way pairing
    const int b  = hb >> 4;
    const int h  = hb & 15;
    const size_t base = (size_t)hb * T_ * HD_;

    const int qw0 = qt * 64 + wave * 16;       // first q-row of this wave

    // Q fragment: 2 d-chunks (Q pre-scaled by QSCALE)
    bf16x8 qf[2];
    {
        const u16* qp = Q + base + (size_t)(qw0 + l16) * HD_ + quad * 8;
        qf[0] = *(const bf16x8*)(qp);
        qf[1] = *(const bf16x8*)(qp + 32);
    }

    bf16x8 onesf;
    #pragma unroll
    for (int i = 0; i < 8; i++) onesf[i] = (short)0x3F80;

    f32x4 o[4];
    #pragma unroll
    for (int d = 0; d < 4; d++) o[d] = (f32x4){0,0,0,0};
    f32x4 accl = (f32x4){0,0,0,0};

    const int nsteps = qt + 1;                 // uniform across waves

    const int srow = t >> 3;                   // 0..31
    const int scol = (t & 7) * 8;              // logical seg * 8
    const int sst  = (((t & 7) ^ (srow & 7)) * 8);  // stored (swizzled) col

    // fragment-read swizzled columns
    const int fs0 = (quad ^ (l16 & 7)) * 8;
    const int fs1 = fs0 ^ 32;

    // shuffle sources for C->A redistribution (r10-verified)
    const int srcA  = l16 + ((quad & 1) << 5);
    const int srcB  = srcA + 16;
    const bool selhi = (quad >> 1) != 0;

    // stage tile 0
    uint4 kr0, kr1, vr0, vr1;
    {
        const u16* kp = K + base + (size_t)srow * HD_ + scol;
        kr0 = *(const uint4*)kp;
        kr1 = *(const uint4*)(kp + 32 * HD_);
        const u16* vp = VT + base + (size_t)srow * T_ + scol;
        vr0 = *(const uint4*)vp;
        vr1 = *(const uint4*)(vp + 32 * T_);
        *(uint4*)&Ks[0][srow][sst]      = kr0;
        *(uint4*)&Ks[0][srow + 32][sst] = kr1;
        *(uint4*)&Vs[0][srow][sst]      = vr0;
        *(uint4*)&Vs[0][srow + 32][sst] = vr1;
    }
    __syncthreads();

    auto compute_tile = [&](int cur, int k0, auto mc) {
        constexpr bool MASKED = decltype(mc)::value;
        // S^T = K_tile . Q^T
        f32x4 st[4];
        __builtin_amdgcn_s_setprio(1);
        #pragma unroll
        for (int j = 0; j < 4; j++) {
            bf16x8 kf0 = *(const bf16x8*)&Ks[cur][j*16 + l16][fs0];
            bf16x8 kf1 = *(const bf16x8*)&Ks[cur][j*16 + l16][fs1];
            f32x4 z = {0,0,0,0};
            z = __builtin_amdgcn_mfma_f32_16x16x32_bf16(kf0, qf[0], z, 0, 0, 0);
            st[j] = __builtin_amdgcn_mfma_f32_16x16x32_bf16(kf1, qf[1], z, 0, 0, 0);
        }
        __builtin_amdgcn_s_setprio(0);

        // V fragments hoisted: independent of pf -> LDS pipe overlaps these
        // 8 ds_read_b128 with the bpermute chain below
        bf16x8 vf0[4], vf1[4];
        #pragma unroll
        for (int d = 0; d < 4; d++) {
            vf0[d] = *(const bf16x8*)&Vs[cur][d*16 + l16][fs0];
            vf1[d] = *(const bf16x8*)&Vs[cur][d*16 + l16][fs1];
        }

        // exp2 (+ mask, compile-time gated) + packed bf16
        u32 p01[4], p23[4];
        const int qi = qw0 + l16;
        #pragma unroll
        for (int j = 0; j < 4; j++) {
            const int kb = k0 + j*16 + quad*4;
            float e0 = __builtin_amdgcn_exp2f(st[j][0]);
            float e1 = __builtin_amdgcn_exp2f(st[j][1]);
            float e2 = __builtin_amdgcn_exp2f(st[j][2]);
            float e3 = __builtin_amdgcn_exp2f(st[j][3]);
            if (MASKED) {
                if (kb + 0 > qi) e0 = 0.f;
                if (kb + 1 > qi) e1 = 0.f;
                if (kb + 2 > qi) e2 = 0.f;
                if (kb + 3 > qi) e3 = 0.f;
            }
            p01[j] = pkbf2(e0, e1);
            p23[j] = pkbf2(e2, e3);
        }

        // C->A redistribution via shuffles; then ones-MFMA + PV
        bf16x8 pf[2];
        #pragma unroll
        for (int c = 0; c < 2; c++) {
            u32 t0, t1, r01, r23, r45, r67;
            t0 = (u32)__shfl((int)p01[2*c],   srcA);
            t1 = (u32)__shfl((int)p01[2*c+1], srcA);
            r01 = selhi ? t1 : t0;
            t0 = (u32)__shfl((int)p23[2*c],   srcA);
            t1 = (u32)__shfl((int)p23[2*c+1], srcA);
            r23 = selhi ? t1 : t0;
            t0 = (u32)__shfl((int)p01[2*c],   srcB);
            t1 = (u32)__shfl((int)p01[2*c+1], srcB);
            r45 = selhi ? t1 : t0;
            t0 = (u32)__shfl((int)p23[2*c],   srcB);
            t1 = (u32)__shfl((int)p23[2*c+1], srcB);
            r67 = selhi ? t1 : t0;
            union { u32 u[4]; bf16x8 v; } pk;
            pk.u[0] = r01; pk.u[1] = r23; pk.u[2] = r45; pk.u[3] = r67;
            pf[c] = pk.v;
        }
        __builtin_amdgcn_s_setprio(1);
        accl = __builtin_amdgcn_mfma_f32_16x16x32_bf16(pf[0], onesf, accl, 0, 0, 0);
        accl = __builtin_amdgcn_mfma_f32_16x16x32_bf16(pf[1], onesf, accl, 0, 0, 0);
        #pragma unroll
        for (int d = 0; d < 4; d++) {
            o[d] = __builtin_amdgcn_mfma_f32_16x16x32_bf16(pf[0], vf0[d], o[d], 0, 0, 0);
            o[d] = __builtin_amdgcn_mfma_f32_16x16x32_bf16(pf[1], vf1[d], o[d], 0, 0, 0);
        }
        __builtin_amdgcn_s_setprio(0);
    };

    for (int kt = 0; kt < nsteps; kt++) {
        const int cur = kt & 1;
        const int k0  = kt * 64;
        const bool have_next = (kt + 1 < nsteps);

        if (have_next) {
            const u16* kp = K + base + (size_t)(k0 + 64 + srow) * HD_ + scol;
            kr0 = *(const uint4*)kp;
            kr1 = *(const uint4*)(kp + 32 * HD_);
            const u16* vp = VT + base + (size_t)srow * T_ + k0 + 64 + scol;
            vr0 = *(const uint4*)vp;
            vr1 = *(const uint4*)(vp + 32 * T_);
        }

        if (kt < qt) compute_tile(cur, k0, Fc{});
        else         compute_tile(cur, k0, Tc{});

        if (have_next) {
            const int nxt = cur ^ 1;
            *(uint4*)&Ks[nxt][srow][sst]      = kr0;
            *(uint4*)&Ks[nxt][srow + 32][sst] = kr1;
            *(uint4*)&Vs[nxt][srow][sst]      = vr0;
            *(uint4*)&Vs[nxt][srow + 32][sst] = vr1;
            __syncthreads();
        }
    }

    // epilogue: normalize by ones-MFMA row sums; y1[B,T,D] bf16
    #pragma unroll
    for (int r = 0; r < 4; r++) {
        const float inv = 1.f / accl[r];
        const int qi = qw0 + quad*4 + r;
        u16* yp = y1 + ((size_t)(b * T_ + qi)) * D_ + h * HD_ + l16;
        yp[0]  = f2bf(o[0][r] * inv);
        yp[16] = f2bf(o[1][r] * inv);
        yp[32] = f2bf(o[2][r] * inv);
        yp[48] = f2bf(o[3][r] * inv);
    }
}

// ---------------------------------------------------------------------------
// Choreography, three ws tiers:
//  huge (>= 3*QKV + y1 + WprojT = ~35.7 MB): prep also transposes Wproj into
//    ws; attn -> y1 in ws; 4 dispatches, no memcpy.
//  big  (>= 3*QKV + y1 = ~33.5 MB): y1 in ws; WprojT over dead K after attn.
//  small: y1 over dead xb in d_out; memcpy to dead VT; WprojT over dead K.
// ---------------------------------------------------------------------------
extern "C" void kernel_launch(void* const* d_in, const int* in_sizes, int n_in,
                              void* d_out, int out_size, void* d_ws, size_t ws_size,
                              hipStream_t stream)
{
    const float* x     = (const float*)d_in[0];
    const float* Wqkv  = (const float*)d_in[1];
    const float* bqkv  = (const float*)d_in[2];
    const float* Wproj = (const float*)d_in[3];
    const float* bproj = (const float*)d_in[4];

    u16* scratch = (u16*)d_out;
    u16* xb      = scratch;
    u16* WqkvT   = scratch + (size_t)MROWS * D_;

    const size_t Y1E = (size_t)MROWS * D_;   // y1 elems (== HEADELEMS)
    const size_t WPE = (size_t)D_ * D_;      // WprojT elems

    u16* qkv = (u16*)d_ws;
    u16* Qp  = qkv;
    u16* Kp  = qkv + (size_t)HEADELEMS;
    u16* Vtp = qkv + (size_t)2 * HEADELEMS;

    const bool huge = ws_size >= ((size_t)3 * HEADELEMS + Y1E + WPE) * 2;
    const bool big  = ws_size >= ((size_t)3 * HEADELEMS + Y1E) * 2;

    u16* y1b    = big ? qkv + (size_t)3 * HEADELEMS : scratch;
    u16* y1g    = big ? y1b : Vtp;
    u16* WprojT = huge ? qkv + (size_t)3 * HEADELEMS + Y1E : Kp;

    // 1) fused prep
    prep_kernel<<<huge ? 5120 : 4864, 256, 0, stream>>>(
        x, Wqkv, Wproj, xb, WqkvT, WprojT);

    // 2) QKV GEMM -> Q(prescaled) | K | VT (bf16) in ws; 2D grid, pipelined
    gemm_mfma<1><<<dim3(3*D_/128, MROWS/128), 256, 0, stream>>>(
        xb, WqkvT, bqkv, (void*)qkv, MROWS, 3*D_, D_);

    // 3) attention -> y1 bf16; grid (hb=32, y=32), 64 q-rows/block
    attn_mfma_kernel<<<dim3(NH_*B_, T_/64), 256, 0, stream>>>(Qp, Kp, Vtp, y1b);

    // 4) Wproj transpose (non-huge paths; K dead now)
    if (!huge)
        transpose_conv_kernel<<<dim3(D_/64, D_/64), 256, 0, stream>>>(
            Wproj, WprojT, D_, D_);

    // 5) small-ws fallback: move y1 out of d_out
    if (!big)
        (void)hipMemcpyAsync(y1g, y1b, Y1E * sizeof(u16),
                             hipMemcpyDeviceToDevice, stream);

    // 6) output projection -> fp32 d_out; 64x128 tiles, grid (8,64) = 512
    //    blocks = 2 blocks/CU (was 256 = 1/CU, the worst m102 regime)
    gemm_mfma_64<<<dim3(D_/128, MROWS/64), 128, 0, stream>>>(
        y1g, WprojT, bproj, (float*)d_out, MROWS, D_, D_);
}

// Round 15
// 185.556 us; speedup vs baseline: 1.0483x; 1.0088x over previous
//
#include <hip/hip_runtime.h>
#include <hip/hip_bf16.h>

// Problem constants
#define B_   2
#define T_   2048
#define D_   1024
#define NH_  16
#define HD_  64
#define MROWS (B_*T_)              // 4096
#define HEADELEMS (B_*NH_*T_*HD_)  // 4194304 per Q/K/V tensor

// exp(s/8) = 2^(s * 0.125 * log2 e); folded into Q at the QKV epilogue
#define QSCALE 0.180336880f

typedef unsigned short u16;
typedef unsigned int   u32;

typedef float f32x4  __attribute__((ext_vector_type(4)));
typedef short bf16x8 __attribute__((ext_vector_type(8)));

// async global->LDS, 16 B/lane; LDS dest MUST be wave-uniform (base+lane*16)
#define GLP(g, l) __builtin_amdgcn_global_load_lds(                         \
    (const __attribute__((address_space(1))) void*)(g),                     \
    (__attribute__((address_space(3))) void*)(l), 16, 0, 0)

struct Fc { static constexpr bool value = false; };
struct Tc { static constexpr bool value = true;  };

__device__ __forceinline__ u16 f2bf(float f) {
    u32 x = __float_as_uint(f);
    u32 r = (x + 0x7fffu + ((x >> 16) & 1u)) >> 16;
    return (u16)r;
}
// packed fp32x2 -> bf16x2
__device__ __forceinline__ u32 pkbf2(float a, float b) {
    __hip_bfloat162 h = __float22bfloat162_rn(make_float2(a, b));
    union { __hip_bfloat162 h2; u32 u; } cv; cv.h2 = h; return cv.u;
}

// ---------------------------------------------------------------------------
// Fused prep: [0,4096) x fp32->bf16; [4096,4864) Wqkv -> bf16 T;
// [4864,5120) Wproj -> bf16 T (only launched on the huge-ws path).
// ---------------------------------------------------------------------------
__device__ __forceinline__ void transpose_tile(const float* in, u16* out,
                                               int K, int N, int bx, int by,
                                               int t, float (*Ts)[65])
{
    const int n0 = bx * 64;
    const int k0 = by * 64;
    #pragma unroll
    for (int pass = 0; pass < 4; pass++) {
        const int r = pass * 16 + (t >> 4);
        const int c = (t & 15) * 4;
        float4 v = *(const float4*)(in + (size_t)(k0 + r) * N + n0 + c);
        Ts[r][c] = v.x; Ts[r][c+1] = v.y; Ts[r][c+2] = v.z; Ts[r][c+3] = v.w;
    }
    __syncthreads();
    #pragma unroll
    for (int pass = 0; pass < 2; pass++) {
        const int nn = pass * 32 + (t >> 3);
        const int kk = (t & 7) * 8;
        u16 o[8];
        #pragma unroll
        for (int j = 0; j < 8; j++) o[j] = f2bf(Ts[kk + j][nn]);
        *(uint4*)(out + (size_t)(n0 + nn) * K + k0 + kk) = *(const uint4*)o;
    }
}

__global__ __launch_bounds__(256)
void prep_kernel(const float* __restrict__ x, const float* __restrict__ Wqkv,
                 const float* __restrict__ Wproj, u16* __restrict__ xb,
                 u16* __restrict__ WqkvT, u16* __restrict__ WprojT)
{
    __shared__ float Ts[64][65];
    const int bid = blockIdx.x;
    const int t   = threadIdx.x;
    if (bid < 4096) {
        int i = bid * 256 + t;
        float4 v = ((const float4*)x)[i];
        ushort4 o;
        o.x = f2bf(v.x); o.y = f2bf(v.y); o.z = f2bf(v.z); o.w = f2bf(v.w);
        ((ushort4*)xb)[i] = o;
    } else if (bid < 4096 + 768) {
        int tb = bid - 4096;                   // [3072][1024] T
        transpose_tile(Wqkv, WqkvT, D_, 3*D_, tb % 48, tb / 48, t, Ts);
    } else {
        int tb = bid - 4864;                   // [1024][1024] T
        transpose_tile(Wproj, WprojT, D_, D_, tb % 16, tb / 16, t, Ts);
    }
}

__global__ __launch_bounds__(256)
void transpose_conv_kernel(const float* __restrict__ in, u16* __restrict__ out,
                           int K, int N)
{
    __shared__ float Ts[64][65];
    transpose_tile(in, out, K, N, blockIdx.x, blockIdx.y, threadIdx.x, Ts);
}

// ---------------------------------------------------------------------------
// MFMA GEMM (r10 pipeline, VERIFIED BEST), round-23 change: XCD-BANDED
// block mapping. Default dispatch spreads each by-row's 24 blocks over 8
// XCDs -> every XCD touches all 32 A-panels (8 MB > 4 MB L2) -> FETCH 40 MB
// vs 14.5 MB inputs. New mapping (assumes round-robin xcd = flat%8, the
// m157/HK idiom; bijective, 768%8==0): each XCD owns a contiguous by-band
// (4 A-panels = 1 MB, L2-resident), bx fastest (B streams via L3).
// r9's failure was the OPPOSITE orientation (bx-banded -> A thrash).
// Pipeline per K-step (unchanged): STAGE(buf^1,k+1) -> vmcnt(8) ->
// s_barrier -> ds_read + 32 MFMA -> lgkmcnt(0) -> s_barrier. Staging:
// per-lane global row srow=t>>3, pre-swizzled seg ((t&7)^(srow&7));
// wave-uniform LDS base wave*8 (+32/64/96). Frag read col
// (quad^(l16&7))*8 ^ (kk*32). Conflicts = 0 (r9/r10-verified).
// MODE 0: fp32 row-major + bias. MODE 1: scatter bf16 Q(*QSCALE),K | V^T.
// ---------------------------------------------------------------------------
template <int MODE>
__global__ __launch_bounds__(256)
void gemm_mfma(const u16* __restrict__ A, const u16* __restrict__ BT,
               const float* __restrict__ bias, void* __restrict__ outv,
               int M, int N, int K)
{
    __shared__ u16 As[2][128][64];
    __shared__ u16 Bs[2][128][64];

    const int t    = threadIdx.x;
    const int wave = t >> 6;
    const int lane = t & 63;
    const int l16  = lane & 15;
    const int quad = lane >> 4;

    // XCD-banded mapping: xcd = flat&7 owns by in [xcd*rpx, +rpx), bx fastest
    const int flat = blockIdx.x;
    const int pos  = flat >> 3;
    const int nbx  = N >> 7;                  // N/128 panels
    const int rpx  = (gridDim.x >> 3) / nbx;  // by-rows per XCD
    const int by   = (flat & 7) * rpx + pos / nbx;
    const int bx   = pos % nbx;

    const int m0 = by * 128;
    const int n0 = bx * 128;
    const int mb = (wave >> 1) * 64;
    const int nb = (wave & 1) * 64;

    const int srow = t >> 3;                     // 0..31 (block-wide)
    const int sseg = ((t & 7) ^ (srow & 7)) * 8; // pre-swizzled k-offset
    const int rw8  = wave * 8;                   // wave-uniform LDS row base

    const u16* gA = A  + (size_t)(m0 + srow) * K + sseg;
    const u16* gB = BT + (size_t)(n0 + srow) * K + sseg;

    const int fragcol = (quad ^ (l16 & 7)) * 8;

    f32x4 acc[4][4];
    #pragma unroll
    for (int i = 0; i < 4; i++)
        #pragma unroll
        for (int j = 0; j < 4; j++) acc[i][j] = (f32x4){0,0,0,0};

    auto STAGE = [&](int buf, int k0) {
        GLP(gA + k0,          &As[buf][rw8     ][0]);
        GLP(gA + k0 + 32*K,   &As[buf][rw8 + 32][0]);
        GLP(gA + k0 + 64*K,   &As[buf][rw8 + 64][0]);
        GLP(gA + k0 + 96*K,   &As[buf][rw8 + 96][0]);
        GLP(gB + k0,          &Bs[buf][rw8     ][0]);
        GLP(gB + k0 + 32*K,   &Bs[buf][rw8 + 32][0]);
        GLP(gB + k0 + 64*K,   &Bs[buf][rw8 + 64][0]);
        GLP(gB + k0 + 96*K,   &Bs[buf][rw8 + 96][0]);
    };

    const int nk = K >> 6;

    STAGE(0, 0);
    asm volatile("s_waitcnt vmcnt(0)" ::: "memory");
    __builtin_amdgcn_s_barrier();

    for (int kt = 0; kt < nk; ++kt) {
        const int cur = kt & 1;
        const bool have_next = (kt + 1 < nk);

        if (have_next) {
            STAGE(cur ^ 1, (kt + 1) << 6);
            asm volatile("s_waitcnt vmcnt(8)" ::: "memory");
        } else {
            asm volatile("s_waitcnt vmcnt(0)" ::: "memory");
        }
        __builtin_amdgcn_s_barrier();

        #pragma unroll
        for (int kk = 0; kk < 2; kk++) {
            const int fc = fragcol ^ (kk << 5);
            bf16x8 af[4], bfr[4];
            #pragma unroll
            for (int i = 0; i < 4; i++)
                af[i] = *(const bf16x8*)&As[cur][mb + i*16 + l16][fc];
            #pragma unroll
            for (int j = 0; j < 4; j++)
                bfr[j] = *(const bf16x8*)&Bs[cur][nb + j*16 + l16][fc];

            #pragma unroll
            for (int i = 0; i < 4; i++)
                #pragma unroll
                for (int j = 0; j < 4; j++)
                    acc[i][j] = __builtin_amdgcn_mfma_f32_16x16x32_bf16(
                        af[i], bfr[j], acc[i][j], 0, 0, 0);
        }

        if (have_next) {
            asm volatile("s_waitcnt lgkmcnt(0)" ::: "memory");
            __builtin_amdgcn_s_barrier();
        }
    }

    if (MODE == 0) {
        #pragma unroll
        for (int j = 0; j < 4; j++) {
            const int n = n0 + nb + j*16 + l16;
            const float bv = bias[n];
            #pragma unroll
            for (int i = 0; i < 4; i++) {
                #pragma unroll
                for (int r = 0; r < 4; r++) {
                    const int m = m0 + mb + i*16 + quad*4 + r;
                    ((float*)outv)[(size_t)m * N + n] = acc[i][j][r] + bv;
                }
            }
        }
    } else {
        const int sec = n0 >> 10;        // block-uniform: 0=q 1=k 2=v
        const int b   = m0 >> 11;        // block-uniform batch index
        const int tb  = m0 & 2047;
        if (sec < 2) {
            const float qs = (sec == 0) ? QSCALE : 1.f;
            #pragma unroll
            for (int j = 0; j < 4; j++) {
                const int n  = n0 + nb + j*16 + l16;
                const float bv = bias[n];
                const int dd = n & 1023;
                const int h  = dd >> 6;
                const int hd = dd & 63;
                u16* op = (u16*)outv + (size_t)sec * HEADELEMS
                        + ((size_t)(b*NH_ + h)) * T_ * HD_ + hd;
                #pragma unroll
                for (int i = 0; i < 4; i++) {
                    #pragma unroll
                    for (int r = 0; r < 4; r++) {
                        const int tt = tb + mb + i*16 + quad*4 + r;
                        op[(size_t)tt * HD_] = f2bf((acc[i][j][r] + bv) * qs);
                    }
                }
            }
        } else {
            #pragma unroll
            for (int j = 0; j < 4; j++) {
                const int n  = n0 + nb + j*16 + l16;
                const float bv = bias[n];
                const int dd = n & 1023;
                const int h  = dd >> 6;
                const int hd = dd & 63;
                u16* vp = (u16*)outv + (size_t)2 * HEADELEMS
                        + ((size_t)(b*NH_ + h)) * T_ * HD_
                        + (size_t)hd * T_ + tb + mb;
                #pragma unroll
                for (int i = 0; i < 4; i++) {
                    u16 o[4];
                    #pragma unroll
                    for (int r = 0; r < 4; r++) o[r] = f2bf(acc[i][j][r] + bv);
                    *(uint2*)(vp + i*16 + quad*4) = *(const uint2*)o;
                }
            }
        }
    }
}

// ---------------------------------------------------------------------------
// Proj GEMM (r14 config): 64x128 tile / 2-wave / BK=64, counted-vmcnt
// pipeline, 512 blocks = 2/CU. Round-23 add: same XCD-banded mapping
// (by-band of 8 per XCD, bx fastest). fp32 row-major + bias epilogue.
// ---------------------------------------------------------------------------
__global__ __launch_bounds__(128)
void gemm_mfma_64(const u16* __restrict__ A, const u16* __restrict__ BT,
                  const float* __restrict__ bias, float* __restrict__ out,
                  int M, int N, int K)
{
    __shared__ u16 As[2][64][64];
    __shared__ u16 Bs[2][128][64];

    const int t    = threadIdx.x;
    const int wave = t >> 6;           // 0..1
    const int lane = t & 63;
    const int l16  = lane & 15;
    const int quad = lane >> 4;

    // XCD-banded mapping: by-band per XCD, bx fastest
    const int flat = blockIdx.x;
    const int pos  = flat >> 3;
    const int nbx  = N >> 7;                  // N/128 panels (8)
    const int rpx  = (gridDim.x >> 3) / nbx;  // by-rows per XCD (8)
    const int by   = (flat & 7) * rpx + pos / nbx;
    const int bx   = pos % nbx;

    const int m0 = by * 64;
    const int n0 = bx * 128;
    const int nb = wave * 64;

    const int lrow = lane >> 3;                   // 0..7
    const int sseg = ((lane & 7) ^ lrow) * 8;     // pre-swizzled k-offset
    const int ra   = wave * 32;                   // A LDS row base
    const int rb   = wave * 64;                   // B LDS row base

    const u16* gA = A  + (size_t)(m0 + ra + lrow) * K + sseg;
    const u16* gB = BT + (size_t)(n0 + rb + lrow) * K + sseg;

    const int fragcol = (quad ^ (l16 & 7)) * 8;

    f32x4 acc[4][4];
    #pragma unroll
    for (int i = 0; i < 4; i++)
        #pragma unroll
        for (int j = 0; j < 4; j++) acc[i][j] = (f32x4){0,0,0,0};

    // per-wave 12 GLPs: 4 for A (32 rows), 8 for B (64 rows)
    auto STAGE = [&](int buf, int k0) {
        GLP(gA + k0,         &As[buf][ra     ][0]);
        GLP(gA + k0 +  8*K,  &As[buf][ra +  8][0]);
        GLP(gA + k0 + 16*K,  &As[buf][ra + 16][0]);
        GLP(gA + k0 + 24*K,  &As[buf][ra + 24][0]);
        GLP(gB + k0,         &Bs[buf][rb     ][0]);
        GLP(gB + k0 +  8*K,  &Bs[buf][rb +  8][0]);
        GLP(gB + k0 + 16*K,  &Bs[buf][rb + 16][0]);
        GLP(gB + k0 + 24*K,  &Bs[buf][rb + 24][0]);
        GLP(gB + k0 + 32*K,  &Bs[buf][rb + 32][0]);
        GLP(gB + k0 + 40*K,  &Bs[buf][rb + 40][0]);
        GLP(gB + k0 + 48*K,  &Bs[buf][rb + 48][0]);
        GLP(gB + k0 + 56*K,  &Bs[buf][rb + 56][0]);
    };

    const int nk = K >> 6;

    STAGE(0, 0);
    asm volatile("s_waitcnt vmcnt(0)" ::: "memory");
    __builtin_amdgcn_s_barrier();

    for (int kt = 0; kt < nk; ++kt) {
        const int cur = kt & 1;
        const bool have_next = (kt + 1 < nk);

        if (have_next) {
            STAGE(cur ^ 1, (kt + 1) << 6);
            asm volatile("s_waitcnt vmcnt(12)" ::: "memory");
        } else {
            asm volatile("s_waitcnt vmcnt(0)" ::: "memory");
        }
        __builtin_amdgcn_s_barrier();

        #pragma unroll
        for (int kk = 0; kk < 2; kk++) {
            const int fc = fragcol ^ (kk << 5);
            bf16x8 af[4], bfr[4];
            #pragma unroll
            for (int i = 0; i < 4; i++)
                af[i] = *(const bf16x8*)&As[cur][i*16 + l16][fc];
            #pragma unroll
            for (int j = 0; j < 4; j++)
                bfr[j] = *(const bf16x8*)&Bs[cur][nb + j*16 + l16][fc];

            #pragma unroll
            for (int i = 0; i < 4; i++)
                #pragma unroll
                for (int j = 0; j < 4; j++)
                    acc[i][j] = __builtin_amdgcn_mfma_f32_16x16x32_bf16(
                        af[i], bfr[j], acc[i][j], 0, 0, 0);
        }

        if (have_next) {
            asm volatile("s_waitcnt lgkmcnt(0)" ::: "memory");
            __builtin_amdgcn_s_barrier();
        }
    }

    #pragma unroll
    for (int j = 0; j < 4; j++) {
        const int n = n0 + nb + j*16 + l16;
        const float bv = bias[n];
        #pragma unroll
        for (int i = 0; i < 4; i++) {
            #pragma unroll
            for (int r = 0; r < 4; r++) {
                const int m = m0 + i*16 + quad*4 + r;
                out[(size_t)m * N + n] = acc[i][j][r] + bv;
            }
        }
    }
}

// ---------------------------------------------------------------------------
// MFMA flash attention v10 (r13 config, VERIFIED BEST): r10 reg-roundtrip
// staging (loads before compute, ds_writes after — implicit T14 split),
// V-fragment ds_reads hoisted before the bpermute chain, [64][64] XOR-seg
// layout (conflict-free), balanced yy->qt mapping (62 tiles/CU), T5
// setprio, ones-MFMA row sums, compile-time masked-tile split.
// ---------------------------------------------------------------------------
__global__ __launch_bounds__(256)
void attn_mfma_kernel(const u16* __restrict__ Q, const u16* __restrict__ K,
                      const u16* __restrict__ VT, u16* __restrict__ y1)
{
    __shared__ u16 Ks[2][64][64];     // [buf][key][d]   (XOR-seg swizzled)
    __shared__ u16 Vs[2][64][64];     // [buf][d][key]   (XOR-seg swizzled)

    const int t    = threadIdx.x;
    const int wave = t >> 6;
    const int lane = t & 63;
    const int l16  = lane & 15;
    const int quad = lane >> 4;

    const int hb = blockIdx.x;                 // b*NH + h (XCD-pinned)
    const int yy = blockIdx.y;
    const int a  = yy & 7, g = yy >> 3;
    const int qt = (g == 0) ? 31 - a : (g == 1) ? 16 + a
                 : (g == 2) ? 15 - a : a;      // balanced 4-way pairing
    const int b  = hb >> 4;
    const int h  = hb & 15;
    const size_t base = (size_t)hb * T_ * HD_;

    const int qw0 = qt * 64 + wave * 16;       // first q-row of this wave

    // Q fragment: 2 d-chunks (Q pre-scaled by QSCALE)
    bf16x8 qf[2];
    {
        const u16* qp = Q + base + (size_t)(qw0 + l16) * HD_ + quad * 8;
        qf[0] = *(const bf16x8*)(qp);
        qf[1] = *(const bf16x8*)(qp + 32);
    }

    bf16x8 onesf;
    #pragma unroll
    for (int i = 0; i < 8; i++) onesf[i] = (short)0x3F80;

    f32x4 o[4];
    #pragma unroll
    for (int d = 0; d < 4; d++) o[d] = (f32x4){0,0,0,0};
    f32x4 accl = (f32x4){0,0,0,0};

    const int nsteps = qt + 1;                 // uniform across waves

    const int srow = t >> 3;                   // 0..31
    const int scol = (t & 7) * 8;              // logical seg * 8
    const int sst  = (((t & 7) ^ (srow & 7)) * 8);  // stored (swizzled) col

    // fragment-read swizzled columns
    const int fs0 = (quad ^ (l16 & 7)) * 8;
    const int fs1 = fs0 ^ 32;

    // shuffle sources for C->A redistribution (r10-verified)
    const int srcA  = l16 + ((quad & 1) << 5);
    const int srcB  = srcA + 16;
    const bool selhi = (quad >> 1) != 0;

    // stage tile 0
    uint4 kr0, kr1, vr0, vr1;
    {
        const u16* kp = K + base + (size_t)srow * HD_ + scol;
        kr0 = *(const uint4*)kp;
        kr1 = *(const uint4*)(kp + 32 * HD_);
        const u16* vp = VT + base + (size_t)srow * T_ + scol;
        vr0 = *(const uint4*)vp;
        vr1 = *(const uint4*)(vp + 32 * T_);
        *(uint4*)&Ks[0][srow][sst]      = kr0;
        *(uint4*)&Ks[0][srow + 32][sst] = kr1;
        *(uint4*)&Vs[0][srow][sst]      = vr0;
        *(uint4*)&Vs[0][srow + 32][sst] = vr1;
    }
    __syncthreads();

    auto compute_tile = [&](int cur, int k0, auto mc) {
        constexpr bool MASKED = decltype(mc)::value;
        // S^T = K_tile . Q^T
        f32x4 st[4];
        __builtin_amdgcn_s_setprio(1);
        #pragma unroll
        for (int j = 0; j < 4; j++) {
            bf16x8 kf0 = *(const bf16x8*)&Ks[cur][j*16 + l16][fs0];
            bf16x8 kf1 = *(const bf16x8*)&Ks[cur][j*16 + l16][fs1];
            f32x4 z = {0,0,0,0};
            z = __builtin_amdgcn_mfma_f32_16x16x32_bf16(kf0, qf[0], z, 0, 0, 0);
            st[j] = __builtin_amdgcn_mfma_f32_16x16x32_bf16(kf1, qf[1], z, 0, 0, 0);
        }
        __builtin_amdgcn_s_setprio(0);

        // V fragments hoisted: independent of pf -> LDS pipe overlaps these
        // 8 ds_read_b128 with the bpermute chain below
        bf16x8 vf0[4], vf1[4];
        #pragma unroll
        for (int d = 0; d < 4; d++) {
            vf0[d] = *(const bf16x8*)&Vs[cur][d*16 + l16][fs0];
            vf1[d] = *(const bf16x8*)&Vs[cur][d*16 + l16][fs1];
        }

        // exp2 (+ mask, compile-time gated) + packed bf16
        u32 p01[4], p23[4];
        const int qi = qw0 + l16;
        #pragma unroll
        for (int j = 0; j < 4; j++) {
            const int kb = k0 + j*16 + quad*4;
            float e0 = __builtin_amdgcn_exp2f(st[j][0]);
            float e1 = __builtin_amdgcn_exp2f(st[j][1]);
            float e2 = __builtin_amdgcn_exp2f(st[j][2]);
            float e3 = __builtin_amdgcn_exp2f(st[j][3]);
            if (MASKED) {
                if (kb + 0 > qi) e0 = 0.f;
                if (kb + 1 > qi) e1 = 0.f;
                if (kb + 2 > qi) e2 = 0.f;
                if (kb + 3 > qi) e3 = 0.f;
            }
            p01[j] = pkbf2(e0, e1);
            p23[j] = pkbf2(e2, e3);
        }

        // C->A redistribution via shuffles; then ones-MFMA + PV
        bf16x8 pf[2];
        #pragma unroll
        for (int c = 0; c < 2; c++) {
            u32 t0, t1, r01, r23, r45, r67;
            t0 = (u32)__shfl((int)p01[2*c],   srcA);
            t1 = (u32)__shfl((int)p01[2*c+1], srcA);
            r01 = selhi ? t1 : t0;
            t0 = (u32)__shfl((int)p23[2*c],   srcA);
            t1 = (u32)__shfl((int)p23[2*c+1], srcA);
            r23 = selhi ? t1 : t0;
            t0 = (u32)__shfl((int)p01[2*c],   srcB);
            t1 = (u32)__shfl((int)p01[2*c+1], srcB);
            r45 = selhi ? t1 : t0;
            t0 = (u32)__shfl((int)p23[2*c],   srcB);
            t1 = (u32)__shfl((int)p23[2*c+1], srcB);
            r67 = selhi ? t1 : t0;
            union { u32 u[4]; bf16x8 v; } pk;
            pk.u[0] = r01; pk.u[1] = r23; pk.u[2] = r45; pk.u[3] = r67;
            pf[c] = pk.v;
        }
        __builtin_amdgcn_s_setprio(1);
        accl = __builtin_amdgcn_mfma_f32_16x16x32_bf16(pf[0], onesf, accl, 0, 0, 0);
        accl = __builtin_amdgcn_mfma_f32_16x16x32_bf16(pf[1], onesf, accl, 0, 0, 0);
        #pragma unroll
        for (int d = 0; d < 4; d++) {
            o[d] = __builtin_amdgcn_mfma_f32_16x16x32_bf16(pf[0], vf0[d], o[d], 0, 0, 0);
            o[d] = __builtin_amdgcn_mfma_f32_16x16x32_bf16(pf[1], vf1[d], o[d], 0, 0, 0);
        }
        __builtin_amdgcn_s_setprio(0);
    };

    for (int kt = 0; kt < nsteps; kt++) {
        const int cur = kt & 1;
        const int k0  = kt * 64;
        const bool have_next = (kt + 1 < nsteps);

        if (have_next) {
            const u16* kp = K + base + (size_t)(k0 + 64 + srow) * HD_ + scol;
            kr0 = *(const uint4*)kp;
            kr1 = *(const uint4*)(kp + 32 * HD_);
            const u16* vp = VT + base + (size_t)srow * T_ + k0 + 64 + scol;
            vr0 = *(const uint4*)vp;
            vr1 = *(const uint4*)(vp + 32 * T_);
        }

        if (kt < qt) compute_tile(cur, k0, Fc{});
        else         compute_tile(cur, k0, Tc{});

        if (have_next) {
            const int nxt = cur ^ 1;
            *(uint4*)&Ks[nxt][srow][sst]      = kr0;
            *(uint4*)&Ks[nxt][srow + 32][sst] = kr1;
            *(uint4*)&Vs[nxt][srow][sst]      = vr0;
            *(uint4*)&Vs[nxt][srow + 32][sst] = vr1;
            __syncthreads();
        }
    }

    // epilogue: normalize by ones-MFMA row sums; y1[B,T,D] bf16
    #pragma unroll
    for (int r = 0; r < 4; r++) {
        const float inv = 1.f / accl[r];
        const int qi = qw0 + quad*4 + r;
        u16* yp = y1 + ((size_t)(b * T_ + qi)) * D_ + h * HD_ + l16;
        yp[0]  = f2bf(o[0][r] * inv);
        yp[16] = f2bf(o[1][r] * inv);
        yp[32] = f2bf(o[2][r] * inv);
        yp[48] = f2bf(o[3][r] * inv);
    }
}

// ---------------------------------------------------------------------------
// Choreography, three ws tiers:
//  huge (>= 3*QKV + y1 + WprojT = ~35.7 MB): prep also transposes Wproj into
//    ws; attn -> y1 in ws; 4 dispatches, no memcpy.
//  big  (>= 3*QKV + y1 = ~33.5 MB): y1 in ws; WprojT over dead K after attn.
//  small: y1 over dead xb in d_out; memcpy to dead VT; WprojT over dead K.
// ---------------------------------------------------------------------------
extern "C" void kernel_launch(void* const* d_in, const int* in_sizes, int n_in,
                              void* d_out, int out_size, void* d_ws, size_t ws_size,
                              hipStream_t stream)
{
    const float* x     = (const float*)d_in[0];
    const float* Wqkv  = (const float*)d_in[1];
    const float* bqkv  = (const float*)d_in[2];
    const float* Wproj = (const float*)d_in[3];
    const float* bproj = (const float*)d_in[4];

    u16* scratch = (u16*)d_out;
    u16* xb      = scratch;
    u16* WqkvT   = scratch + (size_t)MROWS * D_;

    const size_t Y1E = (size_t)MROWS * D_;   // y1 elems (== HEADELEMS)
    const size_t WPE = (size_t)D_ * D_;      // WprojT elems

    u16* qkv = (u16*)d_ws;
    u16* Qp  = qkv;
    u16* Kp  = qkv + (size_t)HEADELEMS;
    u16* Vtp = qkv + (size_t)2 * HEADELEMS;

    const bool huge = ws_size >= ((size_t)3 * HEADELEMS + Y1E + WPE) * 2;
    const bool big  = ws_size >= ((size_t)3 * HEADELEMS + Y1E) * 2;

    u16* y1b    = big ? qkv + (size_t)3 * HEADELEMS : scratch;
    u16* y1g    = big ? y1b : Vtp;
    u16* WprojT = huge ? qkv + (size_t)3 * HEADELEMS + Y1E : Kp;

    // 1) fused prep
    prep_kernel<<<huge ? 5120 : 4864, 256, 0, stream>>>(
        x, Wqkv, Wproj, xb, WqkvT, WprojT);

    // 2) QKV GEMM -> Q(prescaled) | K | VT (bf16) in ws; 1D 768 blocks,
    //    XCD-banded mapping inside
    gemm_mfma<1><<<768, 256, 0, stream>>>(
        xb, WqkvT, bqkv, (void*)qkv, MROWS, 3*D_, D_);

    // 3) attention -> y1 bf16; grid (hb=32, y=32), 64 q-rows/block
    attn_mfma_kernel<<<dim3(NH_*B_, T_/64), 256, 0, stream>>>(Qp, Kp, Vtp, y1b);

    // 4) Wproj transpose (non-huge paths; K dead now)
    if (!huge)
        transpose_conv_kernel<<<dim3(D_/64, D_/64), 256, 0, stream>>>(
            Wproj, WprojT, D_, D_);

    // 5) small-ws fallback: move y1 out of d_out
    if (!big)
        (void)hipMemcpyAsync(y1g, y1b, Y1E * sizeof(u16),
                             hipMemcpyDeviceToDevice, stream);

    // 6) output projection -> fp32 d_out; 1D 512 blocks, XCD-banded mapping
    gemm_mfma_64<<<512, 128, 0, stream>>>(
        y1g, WprojT, bproj, (float*)d_out, MROWS, D_, D_);
}

// Round 16
// 184.153 us; speedup vs baseline: 1.0563x; 1.0076x over previous
//
#include <hip/hip_runtime.h>
#include <hip/hip_bf16.h>

// Problem constants
#define B_   2
#define T_   2048
#define D_   1024
#define NH_  16
#define HD_  64
#define MROWS (B_*T_)              // 4096
#define HEADELEMS (B_*NH_*T_*HD_)  // 4194304 per Q/K/V tensor

// exp(s/8) = 2^(s * 0.125 * log2 e); folded into Q at the QKV epilogue
#define QSCALE 0.180336880f

typedef unsigned short u16;
typedef unsigned int   u32;

typedef float f32x4  __attribute__((ext_vector_type(4)));
typedef short bf16x8 __attribute__((ext_vector_type(8)));

// async global->LDS, 16 B/lane; LDS dest MUST be wave-uniform (base+lane*16)
#define GLP(g, l) __builtin_amdgcn_global_load_lds(                         \
    (const __attribute__((address_space(1))) void*)(g),                     \
    (__attribute__((address_space(3))) void*)(l), 16, 0, 0)

struct Fc { static constexpr bool value = false; };
struct Tc { static constexpr bool value = true;  };

__device__ __forceinline__ u16 f2bf(float f) {
    u32 x = __float_as_uint(f);
    u32 r = (x + 0x7fffu + ((x >> 16) & 1u)) >> 16;
    return (u16)r;
}
// packed fp32x2 -> bf16x2
__device__ __forceinline__ u32 pkbf2(float a, float b) {
    __hip_bfloat162 h = __float22bfloat162_rn(make_float2(a, b));
    union { __hip_bfloat162 h2; u32 u; } cv; cv.h2 = h; return cv.u;
}

// ---------------------------------------------------------------------------
// Fused prep: [0,4096) x fp32->bf16; [4096,4864) Wqkv -> bf16 T;
// [4864,5120) Wproj -> bf16 T (only launched on the huge-ws path).
// ---------------------------------------------------------------------------
__device__ __forceinline__ void transpose_tile(const float* in, u16* out,
                                               int K, int N, int bx, int by,
                                               int t, float (*Ts)[65])
{
    const int n0 = bx * 64;
    const int k0 = by * 64;
    #pragma unroll
    for (int pass = 0; pass < 4; pass++) {
        const int r = pass * 16 + (t >> 4);
        const int c = (t & 15) * 4;
        float4 v = *(const float4*)(in + (size_t)(k0 + r) * N + n0 + c);
        Ts[r][c] = v.x; Ts[r][c+1] = v.y; Ts[r][c+2] = v.z; Ts[r][c+3] = v.w;
    }
    __syncthreads();
    #pragma unroll
    for (int pass = 0; pass < 2; pass++) {
        const int nn = pass * 32 + (t >> 3);
        const int kk = (t & 7) * 8;
        u16 o[8];
        #pragma unroll
        for (int j = 0; j < 8; j++) o[j] = f2bf(Ts[kk + j][nn]);
        *(uint4*)(out + (size_t)(n0 + nn) * K + k0 + kk) = *(const uint4*)o;
    }
}

__global__ __launch_bounds__(256)
void prep_kernel(const float* __restrict__ x, const float* __restrict__ Wqkv,
                 const float* __restrict__ Wproj, u16* __restrict__ xb,
                 u16* __restrict__ WqkvT, u16* __restrict__ WprojT)
{
    __shared__ float Ts[64][65];
    const int bid = blockIdx.x;
    const int t   = threadIdx.x;
    if (bid < 4096) {
        int i = bid * 256 + t;
        float4 v = ((const float4*)x)[i];
        ushort4 o;
        o.x = f2bf(v.x); o.y = f2bf(v.y); o.z = f2bf(v.z); o.w = f2bf(v.w);
        ((ushort4*)xb)[i] = o;
    } else if (bid < 4096 + 768) {
        int tb = bid - 4096;                   // [3072][1024] T
        transpose_tile(Wqkv, WqkvT, D_, 3*D_, tb % 48, tb / 48, t, Ts);
    } else {
        int tb = bid - 4864;                   // [1024][1024] T
        transpose_tile(Wproj, WprojT, D_, D_, tb % 16, tb / 16, t, Ts);
    }
}

__global__ __launch_bounds__(256)
void transpose_conv_kernel(const float* __restrict__ in, u16* __restrict__ out,
                           int K, int N)
{
    __shared__ float Ts[64][65];
    transpose_tile(in, out, K, N, blockIdx.x, blockIdx.y, threadIdx.x, Ts);
}

// ---------------------------------------------------------------------------
// MFMA GEMM (r10/r14 config, VERIFIED BEST — round-24 reverts r15's banded
// mapping, which RAISED FETCH 40->54 MB and cost 1.4 µs; the %8 XCD-assign
// assumption failed on the 768-block grid). 2D grid (bx = N-panel fastest,
// the proven 40 MB L2 pattern) + counted-vmcnt double-buffered pipeline on
// 128x128 / 4-wave / BK=64. Per K-step: STAGE(buf^1,k+1) -> vmcnt(8) ->
// s_barrier -> ds_read + 32 MFMA -> lgkmcnt(0) -> s_barrier. Never drains
// vmcnt to 0 in-loop. Staging: per-lane global row srow=t>>3, pre-swizzled
// seg ((t&7)^(srow&7)); wave-uniform LDS base wave*8 (+32/64/96). Frag
// read col (quad^(l16&7))*8 ^ (kk*32). Conflicts = 0 (r9/r10-verified).
// MODE 0: fp32 row-major + bias. MODE 1: scatter bf16 Q(*QSCALE),K | V^T.
// ---------------------------------------------------------------------------
template <int MODE>
__global__ __launch_bounds__(256)
void gemm_mfma(const u16* __restrict__ A, const u16* __restrict__ BT,
               const float* __restrict__ bias, void* __restrict__ outv,
               int M, int N, int K)
{
    __shared__ u16 As[2][128][64];
    __shared__ u16 Bs[2][128][64];

    const int t    = threadIdx.x;
    const int wave = t >> 6;
    const int lane = t & 63;
    const int l16  = lane & 15;
    const int quad = lane >> 4;

    const int m0 = blockIdx.y * 128;
    const int n0 = blockIdx.x * 128;
    const int mb = (wave >> 1) * 64;
    const int nb = (wave & 1) * 64;

    const int srow = t >> 3;                     // 0..31 (block-wide)
    const int sseg = ((t & 7) ^ (srow & 7)) * 8; // pre-swizzled k-offset
    const int rw8  = wave * 8;                   // wave-uniform LDS row base

    const u16* gA = A  + (size_t)(m0 + srow) * K + sseg;
    const u16* gB = BT + (size_t)(n0 + srow) * K + sseg;

    const int fragcol = (quad ^ (l16 & 7)) * 8;

    f32x4 acc[4][4];
    #pragma unroll
    for (int i = 0; i < 4; i++)
        #pragma unroll
        for (int j = 0; j < 4; j++) acc[i][j] = (f32x4){0,0,0,0};

    auto STAGE = [&](int buf, int k0) {
        GLP(gA + k0,          &As[buf][rw8     ][0]);
        GLP(gA + k0 + 32*K,   &As[buf][rw8 + 32][0]);
        GLP(gA + k0 + 64*K,   &As[buf][rw8 + 64][0]);
        GLP(gA + k0 + 96*K,   &As[buf][rw8 + 96][0]);
        GLP(gB + k0,          &Bs[buf][rw8     ][0]);
        GLP(gB + k0 + 32*K,   &Bs[buf][rw8 + 32][0]);
        GLP(gB + k0 + 64*K,   &Bs[buf][rw8 + 64][0]);
        GLP(gB + k0 + 96*K,   &Bs[buf][rw8 + 96][0]);
    };

    const int nk = K >> 6;

    STAGE(0, 0);
    asm volatile("s_waitcnt vmcnt(0)" ::: "memory");
    __builtin_amdgcn_s_barrier();

    for (int kt = 0; kt < nk; ++kt) {
        const int cur = kt & 1;
        const bool have_next = (kt + 1 < nk);

        if (have_next) {
            STAGE(cur ^ 1, (kt + 1) << 6);
            asm volatile("s_waitcnt vmcnt(8)" ::: "memory");
        } else {
            asm volatile("s_waitcnt vmcnt(0)" ::: "memory");
        }
        __builtin_amdgcn_s_barrier();

        #pragma unroll
        for (int kk = 0; kk < 2; kk++) {
            const int fc = fragcol ^ (kk << 5);
            bf16x8 af[4], bfr[4];
            #pragma unroll
            for (int i = 0; i < 4; i++)
                af[i] = *(const bf16x8*)&As[cur][mb + i*16 + l16][fc];
            #pragma unroll
            for (int j = 0; j < 4; j++)
                bfr[j] = *(const bf16x8*)&Bs[cur][nb + j*16 + l16][fc];

            #pragma unroll
            for (int i = 0; i < 4; i++)
                #pragma unroll
                for (int j = 0; j < 4; j++)
                    acc[i][j] = __builtin_amdgcn_mfma_f32_16x16x32_bf16(
                        af[i], bfr[j], acc[i][j], 0, 0, 0);
        }

        if (have_next) {
            asm volatile("s_waitcnt lgkmcnt(0)" ::: "memory");
            __builtin_amdgcn_s_barrier();
        }
    }

    if (MODE == 0) {
        #pragma unroll
        for (int j = 0; j < 4; j++) {
            const int n = n0 + nb + j*16 + l16;
            const float bv = bias[n];
            #pragma unroll
            for (int i = 0; i < 4; i++) {
                #pragma unroll
                for (int r = 0; r < 4; r++) {
                    const int m = m0 + mb + i*16 + quad*4 + r;
                    ((float*)outv)[(size_t)m * N + n] = acc[i][j][r] + bv;
                }
            }
        }
    } else {
        const int sec = n0 >> 10;        // block-uniform: 0=q 1=k 2=v
        const int b   = m0 >> 11;        // block-uniform batch index
        const int tb  = m0 & 2047;
        if (sec < 2) {
            const float qs = (sec == 0) ? QSCALE : 1.f;
            #pragma unroll
            for (int j = 0; j < 4; j++) {
                const int n  = n0 + nb + j*16 + l16;
                const float bv = bias[n];
                const int dd = n & 1023;
                const int h  = dd >> 6;
                const int hd = dd & 63;
                u16* op = (u16*)outv + (size_t)sec * HEADELEMS
                        + ((size_t)(b*NH_ + h)) * T_ * HD_ + hd;
                #pragma unroll
                for (int i = 0; i < 4; i++) {
                    #pragma unroll
                    for (int r = 0; r < 4; r++) {
                        const int tt = tb + mb + i*16 + quad*4 + r;
                        op[(size_t)tt * HD_] = f2bf((acc[i][j][r] + bv) * qs);
                    }
                }
            }
        } else {
            #pragma unroll
            for (int j = 0; j < 4; j++) {
                const int n  = n0 + nb + j*16 + l16;
                const float bv = bias[n];
                const int dd = n & 1023;
                const int h  = dd >> 6;
                const int hd = dd & 63;
                u16* vp = (u16*)outv + (size_t)2 * HEADELEMS
                        + ((size_t)(b*NH_ + h)) * T_ * HD_
                        + (size_t)hd * T_ + tb + mb;
                #pragma unroll
                for (int i = 0; i < 4; i++) {
                    u16 o[4];
                    #pragma unroll
                    for (int r = 0; r < 4; r++) o[r] = f2bf(acc[i][j][r] + bv);
                    *(uint2*)(vp + i*16 + quad*4) = *(const uint2*)o;
                }
            }
        }
    }
}

// ---------------------------------------------------------------------------
// Proj GEMM (r15 config, KEPT — the r15 win came from here): 64x128 tile /
// 2-wave / BK=64, counted-vmcnt pipeline, 512 blocks = 2/CU, XCD-banded
// mapping (by-band of 8 per XCD = 1 MB A in L2, bx fastest; B = 2 MB
// L2-resident). fp32 row-major + bias epilogue.
// ---------------------------------------------------------------------------
__global__ __launch_bounds__(128)
void gemm_mfma_64(const u16* __restrict__ A, const u16* __restrict__ BT,
                  const float* __restrict__ bias, float* __restrict__ out,
                  int M, int N, int K)
{
    __shared__ u16 As[2][64][64];
    __shared__ u16 Bs[2][128][64];

    const int t    = threadIdx.x;
    const int wave = t >> 6;           // 0..1
    const int lane = t & 63;
    const int l16  = lane & 15;
    const int quad = lane >> 4;

    // XCD-banded mapping: by-band per XCD, bx fastest
    const int flat = blockIdx.x;
    const int pos  = flat >> 3;
    const int nbx  = N >> 7;                  // N/128 panels (8)
    const int rpx  = (gridDim.x >> 3) / nbx;  // by-rows per XCD (8)
    const int by   = (flat & 7) * rpx + pos / nbx;
    const int bx   = pos % nbx;

    const int m0 = by * 64;
    const int n0 = bx * 128;
    const int nb = wave * 64;

    const int lrow = lane >> 3;                   // 0..7
    const int sseg = ((lane & 7) ^ lrow) * 8;     // pre-swizzled k-offset
    const int ra   = wave * 32;                   // A LDS row base
    const int rb   = wave * 64;                   // B LDS row base

    const u16* gA = A  + (size_t)(m0 + ra + lrow) * K + sseg;
    const u16* gB = BT + (size_t)(n0 + rb + lrow) * K + sseg;

    const int fragcol = (quad ^ (l16 & 7)) * 8;

    f32x4 acc[4][4];
    #pragma unroll
    for (int i = 0; i < 4; i++)
        #pragma unroll
        for (int j = 0; j < 4; j++) acc[i][j] = (f32x4){0,0,0,0};

    // per-wave 12 GLPs: 4 for A (32 rows), 8 for B (64 rows)
    auto STAGE = [&](int buf, int k0) {
        GLP(gA + k0,         &As[buf][ra     ][0]);
        GLP(gA + k0 +  8*K,  &As[buf][ra +  8][0]);
        GLP(gA + k0 + 16*K,  &As[buf][ra + 16][0]);
        GLP(gA + k0 + 24*K,  &As[buf][ra + 24][0]);
        GLP(gB + k0,         &Bs[buf][rb     ][0]);
        GLP(gB + k0 +  8*K,  &Bs[buf][rb +  8][0]);
        GLP(gB + k0 + 16*K,  &Bs[buf][rb + 16][0]);
        GLP(gB + k0 + 24*K,  &Bs[buf][rb + 24][0]);
        GLP(gB + k0 + 32*K,  &Bs[buf][rb + 32][0]);
        GLP(gB + k0 + 40*K,  &Bs[buf][rb + 40][0]);
        GLP(gB + k0 + 48*K,  &Bs[buf][rb + 48][0]);
        GLP(gB + k0 + 56*K,  &Bs[buf][rb + 56][0]);
    };

    const int nk = K >> 6;

    STAGE(0, 0);
    asm volatile("s_waitcnt vmcnt(0)" ::: "memory");
    __builtin_amdgcn_s_barrier();

    for (int kt = 0; kt < nk; ++kt) {
        const int cur = kt & 1;
        const bool have_next = (kt + 1 < nk);

        if (have_next) {
            STAGE(cur ^ 1, (kt + 1) << 6);
            asm volatile("s_waitcnt vmcnt(12)" ::: "memory");
        } else {
            asm volatile("s_waitcnt vmcnt(0)" ::: "memory");
        }
        __builtin_amdgcn_s_barrier();

        #pragma unroll
        for (int kk = 0; kk < 2; kk++) {
            const int fc = fragcol ^ (kk << 5);
            bf16x8 af[4], bfr[4];
            #pragma unroll
            for (int i = 0; i < 4; i++)
                af[i] = *(const bf16x8*)&As[cur][i*16 + l16][fc];
            #pragma unroll
            for (int j = 0; j < 4; j++)
                bfr[j] = *(const bf16x8*)&Bs[cur][nb + j*16 + l16][fc];

            #pragma unroll
            for (int i = 0; i < 4; i++)
                #pragma unroll
                for (int j = 0; j < 4; j++)
                    acc[i][j] = __builtin_amdgcn_mfma_f32_16x16x32_bf16(
                        af[i], bfr[j], acc[i][j], 0, 0, 0);
        }

        if (have_next) {
            asm volatile("s_waitcnt lgkmcnt(0)" ::: "memory");
            __builtin_amdgcn_s_barrier();
        }
    }

    #pragma unroll
    for (int j = 0; j < 4; j++) {
        const int n = n0 + nb + j*16 + l16;
        const float bv = bias[n];
        #pragma unroll
        for (int i = 0; i < 4; i++) {
            #pragma unroll
            for (int r = 0; r < 4; r++) {
                const int m = m0 + i*16 + quad*4 + r;
                out[(size_t)m * N + n] = acc[i][j][r] + bv;
            }
        }
    }
}

// ---------------------------------------------------------------------------
// MFMA flash attention v10 (r13 config, VERIFIED BEST): r10 reg-roundtrip
// staging (loads before compute, ds_writes after — implicit T14 split),
// V-fragment ds_reads hoisted before the bpermute chain, [64][64] XOR-seg
// layout (conflict-free), balanced yy->qt mapping (62 tiles/CU), T5
// setprio, ones-MFMA row sums, compile-time masked-tile split.
// ---------------------------------------------------------------------------
__global__ __launch_bounds__(256)
void attn_mfma_kernel(const u16* __restrict__ Q, const u16* __restrict__ K,
                      const u16* __restrict__ VT, u16* __restrict__ y1)
{
    __shared__ u16 Ks[2][64][64];     // [buf][key][d]   (XOR-seg swizzled)
    __shared__ u16 Vs[2][64][64];     // [buf][d][key]   (XOR-seg swizzled)

    const int t    = threadIdx.x;
    const int wave = t >> 6;
    const int lane = t & 63;
    const int l16  = lane & 15;
    const int quad = lane >> 4;

    const int hb = blockIdx.x;                 // b*NH + h (XCD-pinned)
    const int yy = blockIdx.y;
    const int a  = yy & 7, g = yy >> 3;
    const int qt = (g == 0) ? 31 - a : (g == 1) ? 16 + a
                 : (g == 2) ? 15 - a : a;      // balanced 4-way pairing
    const int b  = hb >> 4;
    const int h  = hb & 15;
    const size_t base = (size_t)hb * T_ * HD_;

    const int qw0 = qt * 64 + wave * 16;       // first q-row of this wave

    // Q fragment: 2 d-chunks (Q pre-scaled by QSCALE)
    bf16x8 qf[2];
    {
        const u16* qp = Q + base + (size_t)(qw0 + l16) * HD_ + quad * 8;
        qf[0] = *(const bf16x8*)(qp);
        qf[1] = *(const bf16x8*)(qp + 32);
    }

    bf16x8 onesf;
    #pragma unroll
    for (int i = 0; i < 8; i++) onesf[i] = (short)0x3F80;

    f32x4 o[4];
    #pragma unroll
    for (int d = 0; d < 4; d++) o[d] = (f32x4){0,0,0,0};
    f32x4 accl = (f32x4){0,0,0,0};

    const int nsteps = qt + 1;                 // uniform across waves

    const int srow = t >> 3;                   // 0..31
    const int scol = (t & 7) * 8;              // logical seg * 8
    const int sst  = (((t & 7) ^ (srow & 7)) * 8);  // stored (swizzled) col

    // fragment-read swizzled columns
    const int fs0 = (quad ^ (l16 & 7)) * 8;
    const int fs1 = fs0 ^ 32;

    // shuffle sources for C->A redistribution (r10-verified)
    const int srcA  = l16 + ((quad & 1) << 5);
    const int srcB  = srcA + 16;
    const bool selhi = (quad >> 1) != 0;

    // stage tile 0
    uint4 kr0, kr1, vr0, vr1;
    {
        const u16* kp = K + base + (size_t)srow * HD_ + scol;
        kr0 = *(const uint4*)kp;
        kr1 = *(const uint4*)(kp + 32 * HD_);
        const u16* vp = VT + base + (size_t)srow * T_ + scol;
        vr0 = *(const uint4*)vp;
        vr1 = *(const uint4*)(vp + 32 * T_);
        *(uint4*)&Ks[0][srow][sst]      = kr0;
        *(uint4*)&Ks[0][srow + 32][sst] = kr1;
        *(uint4*)&Vs[0][srow][sst]      = vr0;
        *(uint4*)&Vs[0][srow + 32][sst] = vr1;
    }
    __syncthreads();

    auto compute_tile = [&](int cur, int k0, auto mc) {
        constexpr bool MASKED = decltype(mc)::value;
        // S^T = K_tile . Q^T
        f32x4 st[4];
        __builtin_amdgcn_s_setprio(1);
        #pragma unroll
        for (int j = 0; j < 4; j++) {
            bf16x8 kf0 = *(const bf16x8*)&Ks[cur][j*16 + l16][fs0];
            bf16x8 kf1 = *(const bf16x8*)&Ks[cur][j*16 + l16][fs1];
            f32x4 z = {0,0,0,0};
            z = __builtin_amdgcn_mfma_f32_16x16x32_bf16(kf0, qf[0], z, 0, 0, 0);
            st[j] = __builtin_amdgcn_mfma_f32_16x16x32_bf16(kf1, qf[1], z, 0, 0, 0);
        }
        __builtin_amdgcn_s_setprio(0);

        // V fragments hoisted: independent of pf -> LDS pipe overlaps these
        // 8 ds_read_b128 with the bpermute chain below
        bf16x8 vf0[4], vf1[4];
        #pragma unroll
        for (int d = 0; d < 4; d++) {
            vf0[d] = *(const bf16x8*)&Vs[cur][d*16 + l16][fs0];
            vf1[d] = *(const bf16x8*)&Vs[cur][d*16 + l16][fs1];
        }

        // exp2 (+ mask, compile-time gated) + packed bf16
        u32 p01[4], p23[4];
        const int qi = qw0 + l16;
        #pragma unroll
        for (int j = 0; j < 4; j++) {
            const int kb = k0 + j*16 + quad*4;
            float e0 = __builtin_amdgcn_exp2f(st[j][0]);
            float e1 = __builtin_amdgcn_exp2f(st[j][1]);
            float e2 = __builtin_amdgcn_exp2f(st[j][2]);
            float e3 = __builtin_amdgcn_exp2f(st[j][3]);
            if (MASKED) {
                if (kb + 0 > qi) e0 = 0.f;
                if (kb + 1 > qi) e1 = 0.f;
                if (kb + 2 > qi) e2 = 0.f;
                if (kb + 3 > qi) e3 = 0.f;
            }
            p01[j] = pkbf2(e0, e1);
            p23[j] = pkbf2(e2, e3);
        }

        // C->A redistribution via shuffles; then ones-MFMA + PV
        bf16x8 pf[2];
        #pragma unroll
        for (int c = 0; c < 2; c++) {
            u32 t0, t1, r01, r23, r45, r67;
            t0 = (u32)__shfl((int)p01[2*c],   srcA);
            t1 = (u32)__shfl((int)p01[2*c+1], srcA);
            r01 = selhi ? t1 : t0;
            t0 = (u32)__shfl((int)p23[2*c],   srcA);
            t1 = (u32)__shfl((int)p23[2*c+1], srcA);
            r23 = selhi ? t1 : t0;
            t0 = (u32)__shfl((int)p01[2*c],   srcB);
            t1 = (u32)__shfl((int)p01[2*c+1], srcB);
            r45 = selhi ? t1 : t0;
            t0 = (u32)__shfl((int)p23[2*c],   srcB);
            t1 = (u32)__shfl((int)p23[2*c+1], srcB);
            r67 = selhi ? t1 : t0;
            union { u32 u[4]; bf16x8 v; } pk;
            pk.u[0] = r01; pk.u[1] = r23; pk.u[2] = r45; pk.u[3] = r67;
            pf[c] = pk.v;
        }
        __builtin_amdgcn_s_setprio(1);
        accl = __builtin_amdgcn_mfma_f32_16x16x32_bf16(pf[0], onesf, accl, 0, 0, 0);
        accl = __builtin_amdgcn_mfma_f32_16x16x32_bf16(pf[1], onesf, accl, 0, 0, 0);
        #pragma unroll
        for (int d = 0; d < 4; d++) {
            o[d] = __builtin_amdgcn_mfma_f32_16x16x32_bf16(pf[0], vf0[d], o[d], 0, 0, 0);
            o[d] = __builtin_amdgcn_mfma_f32_16x16x32_bf16(pf[1], vf1[d], o[d], 0, 0, 0);
        }
        __builtin_amdgcn_s_setprio(0);
    };

    for (int kt = 0; kt < nsteps; kt++) {
        const int cur = kt & 1;
        const int k0  = kt * 64;
        const bool have_next = (kt + 1 < nsteps);

        if (have_next) {
            const u16* kp = K + base + (size_t)(k0 + 64 + srow) * HD_ + scol;
            kr0 = *(const uint4*)kp;
            kr1 = *(const uint4*)(kp + 32 * HD_);
            const u16* vp = VT + base + (size_t)srow * T_ + k0 + 64 + scol;
            vr0 = *(const uint4*)vp;
            vr1 = *(const uint4*)(vp + 32 * T_);
        }

        if (kt < qt) compute_tile(cur, k0, Fc{});
        else         compute_tile(cur, k0, Tc{});

        if (have_next) {
            const int nxt = cur ^ 1;
            *(uint4*)&Ks[nxt][srow][sst]      = kr0;
            *(uint4*)&Ks[nxt][srow + 32][sst] = kr1;
            *(uint4*)&Vs[nxt][srow][sst]      = vr0;
            *(uint4*)&Vs[nxt][srow + 32][sst] = vr1;
            __syncthreads();
        }
    }

    // epilogue: normalize by ones-MFMA row sums; y1[B,T,D] bf16
    #pragma unroll
    for (int r = 0; r < 4; r++) {
        const float inv = 1.f / accl[r];
        const int qi = qw0 + quad*4 + r;
        u16* yp = y1 + ((size_t)(b * T_ + qi)) * D_ + h * HD_ + l16;
        yp[0]  = f2bf(o[0][r] * inv);
        yp[16] = f2bf(o[1][r] * inv);
        yp[32] = f2bf(o[2][r] * inv);
        yp[48] = f2bf(o[3][r] * inv);
    }
}

// ---------------------------------------------------------------------------
// Choreography, three ws tiers:
//  huge (>= 3*QKV + y1 + WprojT = ~35.7 MB): prep also transposes Wproj into
//    ws; attn -> y1 in ws; 4 dispatches, no memcpy.
//  big  (>= 3*QKV + y1 = ~33.5 MB): y1 in ws; WprojT over dead K after attn.
//  small: y1 over dead xb in d_out; memcpy to dead VT; WprojT over dead K.
// ---------------------------------------------------------------------------
extern "C" void kernel_launch(void* const* d_in, const int* in_sizes, int n_in,
                              void* d_out, int out_size, void* d_ws, size_t ws_size,
                              hipStream_t stream)
{
    const float* x     = (const float*)d_in[0];
    const float* Wqkv  = (const float*)d_in[1];
    const float* bqkv  = (const float*)d_in[2];
    const float* Wproj = (const float*)d_in[3];
    const float* bproj = (const float*)d_in[4];

    u16* scratch = (u16*)d_out;
    u16* xb      = scratch;
    u16* WqkvT   = scratch + (size_t)MROWS * D_;

    const size_t Y1E = (size_t)MROWS * D_;   // y1 elems (== HEADELEMS)
    const size_t WPE = (size_t)D_ * D_;      // WprojT elems

    u16* qkv = (u16*)d_ws;
    u16* Qp  = qkv;
    u16* Kp  = qkv + (size_t)HEADELEMS;
    u16* Vtp = qkv + (size_t)2 * HEADELEMS;

    const bool huge = ws_size >= ((size_t)3 * HEADELEMS + Y1E + WPE) * 2;
    const bool big  = ws_size >= ((size_t)3 * HEADELEMS + Y1E) * 2;

    u16* y1b    = big ? qkv + (size_t)3 * HEADELEMS : scratch;
    u16* y1g    = big ? y1b : Vtp;
    u16* WprojT = huge ? qkv + (size_t)3 * HEADELEMS + Y1E : Kp;

    // 1) fused prep
    prep_kernel<<<huge ? 5120 : 4864, 256, 0, stream>>>(
        x, Wqkv, Wproj, xb, WqkvT, WprojT);

    // 2) QKV GEMM -> Q(prescaled) | K | VT (bf16) in ws; 2D grid (proven
    //    40 MB L2 pattern), pipelined
    gemm_mfma<1><<<dim3(3*D_/128, MROWS/128), 256, 0, stream>>>(
        xb, WqkvT, bqkv, (void*)qkv, MROWS, 3*D_, D_);

    // 3) attention -> y1 bf16; grid (hb=32, y=32), 64 q-rows/block
    attn_mfma_kernel<<<dim3(NH_*B_, T_/64), 256, 0, stream>>>(Qp, Kp, Vtp, y1b);

    // 4) Wproj transpose (non-huge paths; K dead now)
    if (!huge)
        transpose_conv_kernel<<<dim3(D_/64, D_/64), 256, 0, stream>>>(
            Wproj, WprojT, D_, D_);

    // 5) small-ws fallback: move y1 out of d_out
    if (!big)
        (void)hipMemcpyAsync(y1g, y1b, Y1E * sizeof(u16),
                             hipMemcpyDeviceToDevice, stream);

    // 6) output projection -> fp32 d_out; 1D 512 blocks, XCD-banded mapping
    //    (r15's verified win)
    gemm_mfma_64<<<512, 128, 0, stream>>>(
        y1g, WprojT, bproj, (float*)d_out, MROWS, D_, D_);
}